// Round 15
// baseline (446.879 us; speedup 1.0000x reference)
//
#include <hip/hip_runtime.h>
#include <hip/hip_bf16.h>
#include <math.h>

#define B_ 2
#define N_ 16384
#define M_ 2048
#define D_ 256
#define NHEAD_ 8
#define DH_ 32
#define FF_ 512
#define C_ 50
#define HID_ 128
#define HHID_ 256
#define L_ 4
#define EPS_ 1e-5f
#define TOK_ (B_*M_)   // 4096
#define QSCALE_ 0.25507604155757994f

typedef short short8 __attribute__((ext_vector_type(8)));
typedef short short4_t __attribute__((ext_vector_type(4)));
typedef float f32x4 __attribute__((ext_vector_type(4)));

__device__ __forceinline__ short f2bf(float f) {
  union { float f; unsigned u; } c; c.f = f;
  unsigned u = c.u;
  unsigned r = (u + 0x7FFFu + ((u >> 16) & 1u)) >> 16;
  return (short)r;
}
__device__ __forceinline__ float fast_exp2(float x) {
  float r;
  asm("v_exp_f32 %0, %1" : "=v"(r) : "v"(x));
  return r;
}
__device__ __forceinline__ unsigned cvt_pk_bf16(float lo, float hi) {
  unsigned r;
  asm("v_cvt_pk_bf16_f32 %0, %1, %2" : "=v"(r) : "v"(lo), "v"(hi));
  return r;
}

// async global->LDS stage of one 64x32-bf16 tile (4KB) by 256 threads.
__device__ __forceinline__ void stage16(const short* __restrict__ g, short* lds,
                                        int rowStride, int tid) {
  int row = tid >> 2, gr = tid & 3;
  int kg = gr ^ (row & 3);
  __builtin_amdgcn_global_load_lds(
      (const __attribute__((address_space(1))) void*)(g + (size_t)row * rowStride + kg * 8),
      (__attribute__((address_space(3))) void*)(lds + tid * 8),
      16, 0, 0);
}

// ---------------- one-time weight convert + transpose to bf16 [N][K] ----------------
__global__ __launch_bounds__(256) void wconv_all(
    const float* __restrict__ Wq, const float* __restrict__ Wk,
    const float* __restrict__ Wv, const float* __restrict__ Wo,
    const float* __restrict__ W1, const float* __restrict__ W2,
    const float* __restrict__ h1,
    short* __restrict__ WqT, short* __restrict__ WkT,
    short* __restrict__ WvT, short* __restrict__ WoT,
    short* __restrict__ W1T, short* __restrict__ W2T, short* __restrict__ h1T) {
  int bid = blockIdx.x;
  const float* W; short* WT; int Kd, Nd, tn, tk;
  if (bid < 256) {
    int mat = bid >> 6, rem = bid & 63, l = rem >> 4, t = rem & 15;
    W  = (mat == 0 ? Wq : mat == 1 ? Wk : mat == 2 ? Wv : Wo) + l * 65536;
    WT = (mat == 0 ? WqT : mat == 1 ? WkT : mat == 2 ? WvT : WoT) + l * 65536;
    Kd = 256; Nd = 256; tn = t & 3; tk = t >> 2;
  } else if (bid < 384) {
    int rem = bid - 256, l = rem >> 5, t = rem & 31;
    W = W1 + l * 131072; WT = W1T + l * 131072;
    Kd = 256; Nd = 512; tn = t & 7; tk = t >> 3;
  } else if (bid < 512) {
    int rem = bid - 384, l = rem >> 5, t = rem & 31;
    W = W2 + l * 131072; WT = W2T + l * 131072;
    Kd = 512; Nd = 256; tn = t & 3; tk = t >> 2;
  } else {
    int t = bid - 512;
    W = h1; WT = h1T; Kd = 256; Nd = 256; tn = t & 3; tk = t >> 2;
  }
  int n0 = tn * 64, k0 = tk * 64;
  __shared__ short ts[64][72];
  int tid = threadIdx.x;
  #pragma unroll
  for (int i = 0; i < 4; ++i) {
    int r = i * 16 + (tid >> 4);
    int c4 = (tid & 15) * 4;
    float4 v = *(const float4*)&W[(size_t)(k0 + r) * Nd + n0 + c4];
    ts[c4 + 0][r] = f2bf(v.x);
    ts[c4 + 1][r] = f2bf(v.y);
    ts[c4 + 2][r] = f2bf(v.z);
    ts[c4 + 3][r] = f2bf(v.w);
  }
  __syncthreads();
  #pragma unroll
  for (int i = 0; i < 2; ++i) {
    int n = i * 32 + (tid >> 3);
    int kc = (tid & 7) * 8;
    *(short8*)&WT[(size_t)(n0 + n) * Kd + k0 + kc] = *(short8*)&ts[n][kc];
  }
}

// ---------------- fused embed + pos MLP ----------------
__global__ __launch_bounds__(128) void embed_kernel(
    const float* __restrict__ xyz,
    const float* __restrict__ ew1, const float* __restrict__ eb1,
    const float* __restrict__ ew2, const float* __restrict__ eb2,
    const float* __restrict__ pw1, const float* __restrict__ pb1,
    const float* __restrict__ pw2, const float* __restrict__ pb2,
    float* __restrict__ x) {
  int t = blockIdx.x;
  int b = t / M_, m = t % M_;
  const float* p = xyz + ((size_t)b * N_ + (size_t)m * 8) * 3;
  float t0 = p[0], t1 = p[1], t2 = p[2];
  __shared__ float he[HID_], hp[HID_];
  int j = threadIdx.x;
  {
    float a = fmaf(t0, ew1[j], fmaf(t1, ew1[HID_ + j], fmaf(t2, ew1[2 * HID_ + j], eb1[j])));
    he[j] = fmaxf(a, 0.f);
    float c = fmaf(t0, pw1[j], fmaf(t1, pw1[HID_ + j], fmaf(t2, pw1[2 * HID_ + j], pb1[j])));
    hp[j] = fmaxf(c, 0.f);
  }
  __syncthreads();
  for (int d = j; d < D_; d += HID_) {
    float acc = eb2[d] + pb2[d];
    for (int k = 0; k < HID_; ++k) {
      acc = fmaf(he[k], ew2[k * D_ + d], acc);
      acc = fmaf(hp[k], pw2[k * D_ + d], acc);
    }
    x[(size_t)t * D_ + d] = acc;
  }
}

// ---------------- LayerNorm -> bf16, optional fused split-K combine + residual ----------------
__global__ __launch_bounds__(256) void ln_fused(
    const float* __restrict__ x, const float* __restrict__ pa,
    const float* __restrict__ pb, const float* __restrict__ bias,
    const float* __restrict__ s, const float* __restrict__ bb,
    float* __restrict__ xw, short* __restrict__ y16) {
  int r = blockIdx.x * 4 + (threadIdx.x >> 6);
  int t = threadIdx.x & 63;
  float4 v = ((const float4*)(x + (size_t)r * D_))[t];
  if (pa) {
    float4 a = ((const float4*)(pa + (size_t)r * D_))[t];
    float4 c = ((const float4*)(pb + (size_t)r * D_))[t];
    float4 bi = ((const float4*)bias)[t];
    v.x += a.x + c.x + bi.x;
    v.y += a.y + c.y + bi.y;
    v.z += a.z + c.z + bi.z;
    v.w += a.w + c.w + bi.w;
    ((float4*)(xw + (size_t)r * D_))[t] = v;
  }
  float sum = v.x + v.y + v.z + v.w;
  #pragma unroll
  for (int o = 1; o < 64; o <<= 1) sum += __shfl_xor(sum, o, 64);
  float mean = sum * (1.f / D_);
  float dx = v.x - mean, dy = v.y - mean, dz = v.z - mean, dw = v.w - mean;
  float vs = dx * dx + dy * dy + dz * dz + dw * dw;
  #pragma unroll
  for (int o = 1; o < 64; o <<= 1) vs += __shfl_xor(vs, o, 64);
  float inv = 1.0f / sqrtf(vs * (1.f / D_) + EPS_);
  float4 sv = ((const float4*)s)[t];
  float4 bv = ((const float4*)bb)[t];
  short4_t ov;
  ov[0] = f2bf(dx * inv * sv.x + bv.x);
  ov[1] = f2bf(dy * inv * sv.y + bv.y);
  ov[2] = f2bf(dz * inv * sv.z + bv.z);
  ov[3] = f2bf(dw * inv * sv.w + bv.w);
  *(short4_t*)(y16 + (size_t)r * D_ + t * 4) = ov;
}

// ---------------- head2: combine head1 partials + relu, one wave per token ----------------
__global__ __launch_bounds__(256) void head2_kernel(
    const float* __restrict__ pa, const float* __restrict__ pb,
    const float* __restrict__ b1h, const float* __restrict__ w2,
    const float* __restrict__ b2, float* __restrict__ lt) {
  __shared__ float ys[4][HHID_];
  int w = threadIdx.x >> 6, l = threadIdx.x & 63;
  int t = blockIdx.x * 4 + w;
  float4 a = ((const float4*)(pa + (size_t)t * HHID_))[l];
  float4 c = ((const float4*)(pb + (size_t)t * HHID_))[l];
  float4 bi = ((const float4*)b1h)[l];
  float4 v;
  v.x = fmaxf(a.x + c.x + bi.x, 0.f);
  v.y = fmaxf(a.y + c.y + bi.y, 0.f);
  v.z = fmaxf(a.z + c.z + bi.z, 0.f);
  v.w = fmaxf(a.w + c.w + bi.w, 0.f);
  *(float4*)&ys[w][l * 4] = v;
  int cc = l < C_ ? l : 0;
  float a0 = 0.f, a1 = 0.f, a2 = 0.f, a3 = 0.f;
  #pragma unroll 4
  for (int k = 0; k < HHID_; k += 4) {
    a0 = fmaf(ys[w][k + 0], w2[(k + 0) * C_ + cc], a0);
    a1 = fmaf(ys[w][k + 1], w2[(k + 1) * C_ + cc], a1);
    a2 = fmaf(ys[w][k + 2], w2[(k + 2) * C_ + cc], a2);
    a3 = fmaf(ys[w][k + 3], w2[(k + 3) * C_ + cc], a3);
  }
  if (l < C_) lt[(size_t)t * C_ + l] = (a0 + a1) + (a2 + a3) + b2[l];
}

// ---------------- all-bf16 MFMA GEMM: BM=64, BN=64, BK=32, global_load_lds staging ----------------
template <int ACT, int RES>
__device__ __forceinline__ void gemm16_body(
    const short* __restrict__ A16, const short* __restrict__ WT,
    const float* __restrict__ bias, const float* __restrict__ R,
    float* __restrict__ C, short* __restrict__ C16, short* __restrict__ VT,
    float oscale, int K, int Ncols, int m0, int n0) {
  __shared__ short As[64][32];
  __shared__ short Bs[64][32];
  int tid = threadIdx.x;
  int w = tid >> 6, l = tid & 63;
  int lq = l & 15, lg = l >> 4;
  int wr = (w & 1) * 32, wc = (w >> 1) * 32;
  int ga = (lg ^ (lq & 3)) * 8;
  f32x4 acc00 = {0.f, 0.f, 0.f, 0.f};
  f32x4 acc01 = {0.f, 0.f, 0.f, 0.f};
  f32x4 acc10 = {0.f, 0.f, 0.f, 0.f};
  f32x4 acc11 = {0.f, 0.f, 0.f, 0.f};
  for (int kk = 0; kk < K; kk += 32) {
    __syncthreads();
    stage16(A16 + (size_t)m0 * K + kk, &As[0][0], K, tid);
    stage16(WT + (size_t)n0 * K + kk, &Bs[0][0], K, tid);
    __syncthreads();
    short8 a0 = *(short8*)&As[wr + lq][ga];
    short8 a1 = *(short8*)&As[wr + 16 + lq][ga];
    short8 b0 = *(short8*)&Bs[wc + lq][ga];
    short8 b1 = *(short8*)&Bs[wc + 16 + lq][ga];
    acc00 = __builtin_amdgcn_mfma_f32_16x16x32_bf16(a0, b0, acc00, 0, 0, 0);
    acc01 = __builtin_amdgcn_mfma_f32_16x16x32_bf16(a0, b1, acc01, 0, 0, 0);
    acc10 = __builtin_amdgcn_mfma_f32_16x16x32_bf16(a1, b0, acc10, 0, 0, 0);
    acc11 = __builtin_amdgcn_mfma_f32_16x16x32_bf16(a1, b1, acc11, 0, 0, 0);
  }
  #pragma unroll
  for (int fi = 0; fi < 2; ++fi) {
    int row = m0 + wr + fi * 16 + lg * 4;
    #pragma unroll
    for (int fj = 0; fj < 2; ++fj) {
      int col = n0 + wc + fj * 16 + lq;
      short4_t vt4;
      #pragma unroll
      for (int r = 0; r < 4; ++r) {
        float v = (fi == 0 ? (fj == 0 ? acc00[r] : acc01[r])
                           : (fj == 0 ? acc10[r] : acc11[r])) + bias[col];
        if (ACT == 1) v = fmaxf(v, 0.f);
        else if (ACT == 2) v = 0.5f * v * (1.f + erff(v * 0.70710678118654752f));
        if (RES) v += R[(size_t)(row + r) * Ncols + col];
        if (C)   C[(size_t)(row + r) * Ncols + col] = v;
        if (C16) C16[(size_t)(row + r) * Ncols + col] = f2bf(v * oscale);
        if (VT)  vt4[r] = f2bf(v);
      }
      if (VT) {
        int bb = row >> 11, mm = row & (M_ - 1);
        *(short4_t*)&VT[((size_t)(bb * 256 + col)) * M_ + mm] = vt4;
      }
    }
  }
}

template <int ACT, int RES>
__global__ __launch_bounds__(256) void gemm16(
    const short* __restrict__ A16, const short* __restrict__ WT,
    const float* __restrict__ bias, const float* __restrict__ R,
    float* __restrict__ C, short* __restrict__ C16,
    int K, int Ncols) {
  gemm16_body<ACT, RES>(A16, WT, bias, R, C, C16, nullptr, 1.f, K, Ncols,
                        blockIdx.y * 64, blockIdx.x * 64);
}

// split-K partial GEMM
__global__ __launch_bounds__(256) void gemm16_part(
    const short* __restrict__ A16, const short* __restrict__ WT,
    float* __restrict__ P, int K, int Klen, int Ncols) {
  __shared__ short As[64][32];
  __shared__ short Bs[64][32];
  int tid = threadIdx.x;
  int w = tid >> 6, l = tid & 63;
  int lq = l & 15, lg = l >> 4;
  int wr = (w & 1) * 32, wc = (w >> 1) * 32;
  int ga = (lg ^ (lq & 3)) * 8;
  int m0 = blockIdx.y * 64, n0 = blockIdx.x * 64;
  int k0 = blockIdx.z * Klen;
  f32x4 acc00 = {0.f, 0.f, 0.f, 0.f};
  f32x4 acc01 = {0.f, 0.f, 0.f, 0.f};
  f32x4 acc10 = {0.f, 0.f, 0.f, 0.f};
  f32x4 acc11 = {0.f, 0.f, 0.f, 0.f};
  for (int kk = k0; kk < k0 + Klen; kk += 32) {
    __syncthreads();
    stage16(A16 + (size_t)m0 * K + kk, &As[0][0], K, tid);
    stage16(WT + (size_t)n0 * K + kk, &Bs[0][0], K, tid);
    __syncthreads();
    short8 a0 = *(short8*)&As[wr + lq][ga];
    short8 a1 = *(short8*)&As[wr + 16 + lq][ga];
    short8 b0 = *(short8*)&Bs[wc + lq][ga];
    short8 b1 = *(short8*)&Bs[wc + 16 + lq][ga];
    acc00 = __builtin_amdgcn_mfma_f32_16x16x32_bf16(a0, b0, acc00, 0, 0, 0);
    acc01 = __builtin_amdgcn_mfma_f32_16x16x32_bf16(a0, b1, acc01, 0, 0, 0);
    acc10 = __builtin_amdgcn_mfma_f32_16x16x32_bf16(a1, b0, acc10, 0, 0, 0);
    acc11 = __builtin_amdgcn_mfma_f32_16x16x32_bf16(a1, b1, acc11, 0, 0, 0);
  }
  float* Pp = P + (size_t)blockIdx.z * TOK_ * Ncols;
  #pragma unroll
  for (int fi = 0; fi < 2; ++fi) {
    int row = m0 + wr + fi * 16 + lg * 4;
    #pragma unroll
    for (int fj = 0; fj < 2; ++fj) {
      int col = n0 + wc + fj * 16 + lq;
      #pragma unroll
      for (int r = 0; r < 4; ++r) {
        float v = (fi == 0 ? (fj == 0 ? acc00[r] : acc01[r])
                           : (fj == 0 ? acc10[r] : acc11[r]));
        Pp[(size_t)(row + r) * Ncols + col] = v;
      }
    }
  }
}

// QKV: Q -> bf16 scaled by QSCALE_, K -> bf16, V -> bf16 transposed (direct)
__global__ __launch_bounds__(256) void qkv16(
    const short* __restrict__ A16,
    const short* __restrict__ WqT, const short* __restrict__ WkT, const short* __restrict__ WvT,
    const float* __restrict__ bq, const float* __restrict__ bk, const float* __restrict__ bv,
    short* __restrict__ q16, short* __restrict__ k16, short* __restrict__ vt16) {
  int sel = blockIdx.x >> 2;
  int n0 = (blockIdx.x & 3) << 6;
  int m0 = blockIdx.y * 64;
  if (sel == 0) {
    gemm16_body<0, 0>(A16, WqT, bq, nullptr, nullptr, q16, nullptr, QSCALE_, D_, D_, m0, n0);
  } else if (sel == 1) {
    gemm16_body<0, 0>(A16, WkT, bk, nullptr, nullptr, k16, nullptr, 1.f, D_, D_, m0, n0);
  } else {
    gemm16_body<0, 0>(A16, WvT, bv, nullptr, nullptr, nullptr, vt16, 1.f, D_, D_, m0, n0);
  }
}

// ---------------- Wo GEMM, split-K x2, fused attention combine (2 KV-halves) ----------------
__global__ __launch_bounds__(256) void wo_split(
    const float* __restrict__ po0, const float* __restrict__ po1,
    const float* __restrict__ pl, const short* __restrict__ WT,
    float* __restrict__ P) {
  __shared__ short As[64][136];
  __shared__ short Bs[64][32];
  int tid = threadIdx.x;
  int w = tid >> 6, l = tid & 63;
  int m0 = blockIdx.y * 64, n0 = blockIdx.x * 64;
  int half = blockIdx.z;
  int c2 = l * 2;
  int hh = half * 4 + (c2 >> 5);
  int d0 = c2 & 31;
  #pragma unroll 4
  for (int c = 0; c < 16; ++c) {
    int t = w * 16 + c;
    int row = m0 + t;
    int bb = row >> 11, mm = row & (M_ - 1);
    size_t f = (size_t)(bb * NHEAD_ + hh) * M_ + mm;
    float inv = 1.f / (pl[f] + pl[16 * M_ + f]);
    float v0 = (po0[f * 32 + d0] + po1[f * 32 + d0]) * inv;
    float v1 = (po0[f * 32 + d0 + 1] + po1[f * 32 + d0 + 1]) * inv;
    *(unsigned*)&As[t][c2] = cvt_pk_bf16(v0, v1);
  }
  int lq = l & 15, lg = l >> 4;
  int wr = (w & 1) * 32, wc = (w >> 1) * 32;
  int gb = (lg ^ (lq & 3)) * 8;
  f32x4 acc00 = {0.f, 0.f, 0.f, 0.f};
  f32x4 acc01 = {0.f, 0.f, 0.f, 0.f};
  f32x4 acc10 = {0.f, 0.f, 0.f, 0.f};
  f32x4 acc11 = {0.f, 0.f, 0.f, 0.f};
  for (int kk = 0; kk < 128; kk += 32) {
    __syncthreads();
    stage16(WT + (size_t)n0 * D_ + half * 128 + kk, &Bs[0][0], D_, tid);
    __syncthreads();
    short8 a0 = *(short8*)&As[wr + lq][kk + lg * 8];
    short8 a1 = *(short8*)&As[wr + 16 + lq][kk + lg * 8];
    short8 b0 = *(short8*)&Bs[wc + lq][gb];
    short8 b1 = *(short8*)&Bs[wc + 16 + lq][gb];
    acc00 = __builtin_amdgcn_mfma_f32_16x16x32_bf16(a0, b0, acc00, 0, 0, 0);
    acc01 = __builtin_amdgcn_mfma_f32_16x16x32_bf16(a0, b1, acc01, 0, 0, 0);
    acc10 = __builtin_amdgcn_mfma_f32_16x16x32_bf16(a1, b0, acc10, 0, 0, 0);
    acc11 = __builtin_amdgcn_mfma_f32_16x16x32_bf16(a1, b1, acc11, 0, 0, 0);
  }
  float* Pp = P + (size_t)half * TOK_ * D_;
  #pragma unroll
  for (int fi = 0; fi < 2; ++fi) {
    int row = m0 + wr + fi * 16 + lg * 4;
    #pragma unroll
    for (int fj = 0; fj < 2; ++fj) {
      int col = n0 + wc + fj * 16 + lq;
      #pragma unroll
      for (int r = 0; r < 4; ++r) {
        float v = (fi == 0 ? (fj == 0 ? acc00[r] : acc01[r])
                           : (fj == 0 ? acc10[r] : acc11[r]));
        Pp[(size_t)(row + r) * D_ + col] = v;
      }
    }
  }
}

// ---------------- flash attention: no-max exp2 softmax, KV-split x2, KVBLK=128 ----------------
__global__ __launch_bounds__(256) void attn_mfma_kernel(
    const short* __restrict__ q16, const short* __restrict__ k16,
    const short* __restrict__ vt16,
    float* __restrict__ po0, float* __restrict__ po1,
    float* __restrict__ pl) {
  __shared__ short Ks[128][40];
  __shared__ short Vt[32][136];
  __shared__ short Ps[4][16][136];
  int bid = blockIdx.x;
  int half = bid & 1;
  int qt = (bid >> 1) & 31;
  int h  = (bid >> 6) & 7;
  int b  = bid >> 9;
  int tid = threadIdx.x;
  int w  = tid >> 6;
  int l  = tid & 63;
  int lq = l & 15;
  int lg = l >> 4;

  short8 qf = *(const short8*)&q16[(size_t)(b * M_ + qt * 64 + w * 16 + lq) * D_ + h * DH_ + lg * 8];

  float l_i = 0.f;
  f32x4 o0 = {0.f, 0.f, 0.f, 0.f};
  f32x4 o1 = {0.f, 0.f, 0.f, 0.f};
  int srow = tid >> 1, scol = (tid & 1) * 16;
  int vd = tid >> 3, vm = (tid & 7) * 16;
  const short* kp = k16 + (size_t)(b * M_ + half * 1024 + srow) * D_ + h * DH_ + scol;
  const short* vp = vt16 + (size_t)((b * NHEAD_ + h) * DH_ + vd) * M_ + half * 1024 + vm;

  for (int kt = 0; kt < 8; ++kt) {
    __syncthreads();
    {
      const short* kg = kp + (size_t)(kt * 128) * D_;
      *(short8*)&Ks[srow][scol]     = *(const short8*)(kg);
      *(short8*)&Ks[srow][scol + 8] = *(const short8*)(kg + 8);
      const short* vg = vp + kt * 128;
      *(short8*)&Vt[vd][vm]     = *(const short8*)(vg);
      *(short8*)&Vt[vd][vm + 8] = *(const short8*)(vg + 8);
    }
    __syncthreads();
    f32x4 st[8];
    #pragma unroll
    for (int t = 0; t < 8; ++t) {
      short8 kf = *(short8*)&Ks[t * 16 + lq][lg * 8];
      f32x4 z = {0.f, 0.f, 0.f, 0.f};
      st[t] = __builtin_amdgcn_mfma_f32_16x16x32_bf16(kf, qf, z, 0, 0, 0);
    }
    #pragma unroll
    for (int t = 0; t < 8; ++t)
      #pragma unroll
      for (int r2 = 0; r2 < 4; ++r2) {
        st[t][r2] = fast_exp2(st[t][r2]);
        l_i += st[t][r2];
      }
    {
      unsigned* pw = (unsigned*)&Ps[w][lq][0];
      #pragma unroll
      for (int t = 0; t < 8; ++t) {
        uint2 pk;
        pk.x = cvt_pk_bf16(st[t][0], st[t][1]);
        pk.y = cvt_pk_bf16(st[t][2], st[t][3]);
        *(uint2*)(pw + t * 8 + lg * 2) = pk;
      }
    }
    #pragma unroll
    for (int c = 0; c < 4; ++c) {
      short8 pf = *(short8*)&Ps[w][lq][c * 32 + lg * 8];
      short8 v0 = *(short8*)&Vt[lq][c * 32 + lg * 8];
      short8 v1 = *(short8*)&Vt[16 + lq][c * 32 + lg * 8];
      o0 = __builtin_amdgcn_mfma_f32_16x16x32_bf16(v0, pf, o0, 0, 0, 0);
      o1 = __builtin_amdgcn_mfma_f32_16x16x32_bf16(v1, pf, o1, 0, 0, 0);
    }
  }
  l_i += __shfl_xor(l_i, 16, 64);
  l_i += __shfl_xor(l_i, 32, 64);
  int f = (b * NHEAD_ + h) * M_ + qt * 64 + w * 16 + lq;
  float* pp = (half == 0 ? po0 : po1) + (size_t)f * 32;
  #pragma unroll
  for (int r2 = 0; r2 < 4; ++r2) pp[lg * 4 + r2] = o0[r2];
  #pragma unroll
  for (int r2 = 0; r2 < 4; ++r2) pp[16 + lg * 4 + r2] = o1[r2];
  if (lg == 0) pl[half * (16 * M_) + f] = l_i;
}

// ---------------- KNN top-3 + gather/mean: 4-way chunk prefilter ----------------
// 1024 blocks (512/batch), 512 threads, 32 queries/block, 16 lanes/query, chunk=128
__global__ __launch_bounds__(512) void knn_kernel(
    const float* __restrict__ xyz, const float* __restrict__ lt,
    float* __restrict__ out) {
  __shared__ float4 tok[2064];
  int b = blockIdx.x >> 9;
  int q0 = (blockIdx.x & 511) << 5;
  int tid = threadIdx.x;
  for (int i = tid; i < M_; i += 512) {
    const float* tp = xyz + ((size_t)b * N_ + (size_t)i * 8) * 3;
    float a = tp[0], bb = tp[1], cc = tp[2];
    tok[i + (i >> 7)] = make_float4(a, bb, cc, a * a + bb * bb + cc * cc);
  }
  __syncthreads();
  int g = tid >> 4, sl = tid & 15;
  int n = q0 + g;
  const float* qp = xyz + ((size_t)b * N_ + n) * 3;
  float qx = qp[0], qy = qp[1], qz = qp[2];
  float q2 = qx * qx + qy * qy + qz * qz;
  float dd0 = INFINITY, dd1 = INFINITY, dd2 = INFINITY;
  int ii0 = 0, ii1 = 0, ii2 = 0;
  const float4* cp = &tok[sl * 129];
  int mb = sl << 7;
  auto ins = [&](float d, int m) {
    if (d < dd2) {
      if (d < dd1) {
        dd2 = dd1; ii2 = ii1;
        if (d < dd0) { dd1 = dd0; ii1 = ii0; dd0 = d; ii0 = m; }
        else         { dd1 = d;  ii1 = m; }
      } else         { dd2 = d;  ii2 = m; }
    }
  };
  for (int j = 0; j < 128; j += 4) {
    float4 t0 = cp[j], t1 = cp[j + 1], t2 = cp[j + 2], t3 = cp[j + 3];
    float d0 = fmaxf(q2 + t0.w - 2.f * fmaf(qx, t0.x, fmaf(qy, t0.y, qz * t0.z)), 0.f);
    float d1 = fmaxf(q2 + t1.w - 2.f * fmaf(qx, t1.x, fmaf(qy, t1.y, qz * t1.z)), 0.f);
    float d2 = fmaxf(q2 + t2.w - 2.f * fmaf(qx, t2.x, fmaf(qy, t2.y, qz * t2.z)), 0.f);
    float d3 = fmaxf(q2 + t3.w - 2.f * fmaf(qx, t3.x, fmaf(qy, t3.y, qz * t3.z)), 0.f);
    float mn = fminf(fminf(d0, d1), fminf(d2, d3));
    if (mn < dd2) {   // rare after warm-up: chunk contains a top-3 candidate
      ins(d0, mb + j);
      ins(d1, mb + j + 1);
      ins(d2, mb + j + 2);
      ins(d3, mb + j + 3);
    }
  }
  // merge across 16 lanes, lexicographic (d, i) -> exact top_k tie semantics
  auto insT = [&](float d, int i) {
    if (d < dd2 || (d == dd2 && i < ii2)) {
      if (d < dd1 || (d == dd1 && i < ii1)) {
        dd2 = dd1; ii2 = ii1;
        if (d < dd0 || (d == dd0 && i < ii0)) { dd1 = dd0; ii1 = ii0; dd0 = d; ii0 = i; }
        else { dd1 = d; ii1 = i; }
      } else { dd2 = d; ii2 = i; }
    }
  };
  #pragma unroll
  for (int off = 1; off < 16; off <<= 1) {
    float p0 = __shfl_xor(dd0, off, 64); int pi0 = __shfl_xor(ii0, off, 64);
    float p1 = __shfl_xor(dd1, off, 64); int pi1 = __shfl_xor(ii1, off, 64);
    float p2 = __shfl_xor(dd2, off, 64); int pi2 = __shfl_xor(ii2, off, 64);
    insT(p0, pi0); insT(p1, pi1); insT(p2, pi2);
  }
  const float* l0 = lt + ((size_t)b * M_ + ii0) * C_;
  const float* l1 = lt + ((size_t)b * M_ + ii1) * C_;
  const float* l2 = lt + ((size_t)b * M_ + ii2) * C_;
  float* op = out + ((size_t)b * N_ + n) * C_;
  for (int cc = sl; cc < C_; cc += 16)
    op[cc] = (l0[cc] + l1[cc] + l2[cc]) * (1.f / 3.f);
}

extern "C" void kernel_launch(void* const* d_in, const int* in_sizes, int n_in,
                              void* d_out, int out_size, void* d_ws, size_t ws_size,
                              hipStream_t stream) {
  const float* xyz  = (const float*)d_in[0];
  const float* ew1  = (const float*)d_in[1];
  const float* eb1  = (const float*)d_in[2];
  const float* ew2  = (const float*)d_in[3];
  const float* eb2  = (const float*)d_in[4];
  const float* pw1  = (const float*)d_in[5];
  const float* pb1  = (const float*)d_in[6];
  const float* pw2  = (const float*)d_in[7];
  const float* pb2  = (const float*)d_in[8];
  const float* Wq   = (const float*)d_in[9];
  const float* bq   = (const float*)d_in[10];
  const float* Wk   = (const float*)d_in[11];
  const float* bk   = (const float*)d_in[12];
  const float* Wv   = (const float*)d_in[13];
  const float* bv   = (const float*)d_in[14];
  const float* Wo   = (const float*)d_in[15];
  const float* bo   = (const float*)d_in[16];
  const float* ln1s = (const float*)d_in[17];
  const float* ln1b = (const float*)d_in[18];
  const float* W1   = (const float*)d_in[19];
  const float* b1   = (const float*)d_in[20];
  const float* W2   = (const float*)d_in[21];
  const float* b2   = (const float*)d_in[22];
  const float* ln2s = (const float*)d_in[23];
  const float* ln2b = (const float*)d_in[24];
  const float* hw1  = (const float*)d_in[25];
  const float* hb1  = (const float*)d_in[26];
  const float* hw2  = (const float*)d_in[27];
  const float* hb2  = (const float*)d_in[28];
  float* out = (float*)d_out;

  // ---- workspace layout ----
  float* x   = (float*)d_ws;
  float* y   = x + 1048576;
  float* po2 = y + 1048576;
  float* po3 = po2 + 1048576;
  float* lt  = po3 + 1048576;
  short* y16 = (short*)(lt + 204800);
  short* q16 = y16 + 1048576;
  short* k16 = q16 + 1048576;
  short* v16 = k16 + 1048576;
  short* vt16 = v16 + 1048576;
  short* ob16 = vt16 + 1048576;
  short* x16  = ob16 + 1048576;
  short* ff16 = x16 + 1048576;
  short* WqT = ff16 + 2097152;
  short* WkT = WqT + 262144;
  short* WvT = WkT + 262144;
  short* WoT = WvT + 262144;
  short* W1T = WoT + 262144;
  short* W2T = W1T + 524288;
  short* h1T = W2T + 524288;
  float* wpart = (float*)(h1T + 65536);
  float* po0 = y;
  float* po1 = (float*)ff16;
  float* pl  = lt;

  wconv_all<<<528, 256, 0, stream>>>(Wq, Wk, Wv, Wo, W1, W2, hw1,
                                     WqT, WkT, WvT, WoT, W1T, W2T, h1T);
  embed_kernel<<<TOK_, 128, 0, stream>>>(xyz, ew1, eb1, ew2, eb2, pw1, pb1, pw2, pb2, x);

  dim3 gQKV(12, TOK_ / 64);
  dim3 gDs(D_ / 64, TOK_ / 64, 2);
  dim3 gF(FF_ / 64, TOK_ / 64);
  dim3 gD(D_ / 64, TOK_ / 64);
  for (int l = 0; l < L_; ++l) {
    if (l == 0)
      ln_fused<<<TOK_ / 4, 256, 0, stream>>>(x, nullptr, nullptr, nullptr,
                                             ln1s + l * D_, ln1b + l * D_, x, y16);
    else
      ln_fused<<<TOK_ / 4, 256, 0, stream>>>(x, wpart, wpart + (size_t)TOK_ * D_,
                                             b2 + (l - 1) * D_,
                                             ln1s + l * D_, ln1b + l * D_, x, y16);
    qkv16<<<gQKV, 256, 0, stream>>>(y16, WqT + l * 65536, WkT + l * 65536, WvT + l * 65536,
                                    bq + l * D_, bk + l * D_, bv + l * D_, q16, k16, vt16);
    attn_mfma_kernel<<<1024, 256, 0, stream>>>(q16, k16, vt16, po0, po1, pl);
    wo_split<<<gDs, 256, 0, stream>>>(po0, po1, pl, WoT + l * 65536, wpart);
    ln_fused<<<TOK_ / 4, 256, 0, stream>>>(x, wpart, wpart + (size_t)TOK_ * D_,
                                           bo + l * D_,
                                           ln2s + l * D_, ln2b + l * D_, x, y16);
    gemm16<2, 0><<<gF, 256, 0, stream>>>(y16, W1T + l * 131072, b1 + l * FF_, nullptr, nullptr, ff16, D_, FF_);
    if (l < L_ - 1) {
      gemm16_part<<<gDs, 256, 0, stream>>>(ff16, W2T + l * 131072, wpart, FF_, 256, D_);
    } else {
      gemm16<0, 1><<<gD, 256, 0, stream>>>(ff16, W2T + l * 131072, b2 + l * D_, x, x, x16, FF_, D_);
    }
  }
  gemm16_part<<<gDs, 256, 0, stream>>>(x16, h1T, wpart, D_, 128, HHID_);
  head2_kernel<<<TOK_ / 4, 256, 0, stream>>>(wpart, wpart + (size_t)TOK_ * HHID_,
                                             hb1, hw2, hb2, lt);
  knn_kernel<<<1024, 512, 0, stream>>>(xyz, lt, out);
}

// Round 16
// 376.221 us; speedup vs baseline: 1.1878x; 1.1878x over previous
//
#include <hip/hip_runtime.h>
#include <hip/hip_bf16.h>
#include <math.h>

#define B_ 2
#define N_ 16384
#define M_ 2048
#define D_ 256
#define NHEAD_ 8
#define DH_ 32
#define FF_ 512
#define C_ 50
#define HID_ 128
#define HHID_ 256
#define L_ 4
#define EPS_ 1e-5f
#define TOK_ (B_*M_)   // 4096
#define QSCALE_ 0.25507604155757994f

typedef short short8 __attribute__((ext_vector_type(8)));
typedef short short4_t __attribute__((ext_vector_type(4)));
typedef float f32x4 __attribute__((ext_vector_type(4)));

__device__ __forceinline__ short f2bf(float f) {
  union { float f; unsigned u; } c; c.f = f;
  unsigned u = c.u;
  unsigned r = (u + 0x7FFFu + ((u >> 16) & 1u)) >> 16;
  return (short)r;
}
__device__ __forceinline__ float fast_exp2(float x) {
  float r;
  asm("v_exp_f32 %0, %1" : "=v"(r) : "v"(x));
  return r;
}
__device__ __forceinline__ unsigned cvt_pk_bf16(float lo, float hi) {
  unsigned r;
  asm("v_cvt_pk_bf16_f32 %0, %1, %2" : "=v"(r) : "v"(lo), "v"(hi));
  return r;
}

// async global->LDS stage of one 64x32-bf16 tile (4KB) by 256 threads.
__device__ __forceinline__ void stage16(const short* __restrict__ g, short* lds,
                                        int rowStride, int tid) {
  int row = tid >> 2, gr = tid & 3;
  int kg = gr ^ (row & 3);
  __builtin_amdgcn_global_load_lds(
      (const __attribute__((address_space(1))) void*)(g + (size_t)row * rowStride + kg * 8),
      (__attribute__((address_space(3))) void*)(lds + tid * 8),
      16, 0, 0);
}

// ---------------- one-time weight convert + transpose to bf16 [N][K] ----------------
__global__ __launch_bounds__(256) void wconv_all(
    const float* __restrict__ Wq, const float* __restrict__ Wk,
    const float* __restrict__ Wv, const float* __restrict__ Wo,
    const float* __restrict__ W1, const float* __restrict__ W2,
    const float* __restrict__ h1,
    short* __restrict__ WqT, short* __restrict__ WkT,
    short* __restrict__ WvT, short* __restrict__ WoT,
    short* __restrict__ W1T, short* __restrict__ W2T, short* __restrict__ h1T) {
  int bid = blockIdx.x;
  const float* W; short* WT; int Kd, Nd, tn, tk;
  if (bid < 256) {
    int mat = bid >> 6, rem = bid & 63, l = rem >> 4, t = rem & 15;
    W  = (mat == 0 ? Wq : mat == 1 ? Wk : mat == 2 ? Wv : Wo) + l * 65536;
    WT = (mat == 0 ? WqT : mat == 1 ? WkT : mat == 2 ? WvT : WoT) + l * 65536;
    Kd = 256; Nd = 256; tn = t & 3; tk = t >> 2;
  } else if (bid < 384) {
    int rem = bid - 256, l = rem >> 5, t = rem & 31;
    W = W1 + l * 131072; WT = W1T + l * 131072;
    Kd = 256; Nd = 512; tn = t & 7; tk = t >> 3;
  } else if (bid < 512) {
    int rem = bid - 384, l = rem >> 5, t = rem & 31;
    W = W2 + l * 131072; WT = W2T + l * 131072;
    Kd = 512; Nd = 256; tn = t & 3; tk = t >> 2;
  } else {
    int t = bid - 512;
    W = h1; WT = h1T; Kd = 256; Nd = 256; tn = t & 3; tk = t >> 2;
  }
  int n0 = tn * 64, k0 = tk * 64;
  __shared__ short ts[64][72];
  int tid = threadIdx.x;
  #pragma unroll
  for (int i = 0; i < 4; ++i) {
    int r = i * 16 + (tid >> 4);
    int c4 = (tid & 15) * 4;
    float4 v = *(const float4*)&W[(size_t)(k0 + r) * Nd + n0 + c4];
    ts[c4 + 0][r] = f2bf(v.x);
    ts[c4 + 1][r] = f2bf(v.y);
    ts[c4 + 2][r] = f2bf(v.z);
    ts[c4 + 3][r] = f2bf(v.w);
  }
  __syncthreads();
  #pragma unroll
  for (int i = 0; i < 2; ++i) {
    int n = i * 32 + (tid >> 3);
    int kc = (tid & 7) * 8;
    *(short8*)&WT[(size_t)(n0 + n) * Kd + k0 + kc] = *(short8*)&ts[n][kc];
  }
}

// ---------------- fused embed + pos MLP ----------------
__global__ __launch_bounds__(128) void embed_kernel(
    const float* __restrict__ xyz,
    const float* __restrict__ ew1, const float* __restrict__ eb1,
    const float* __restrict__ ew2, const float* __restrict__ eb2,
    const float* __restrict__ pw1, const float* __restrict__ pb1,
    const float* __restrict__ pw2, const float* __restrict__ pb2,
    float* __restrict__ x) {
  int t = blockIdx.x;
  int b = t / M_, m = t % M_;
  const float* p = xyz + ((size_t)b * N_ + (size_t)m * 8) * 3;
  float t0 = p[0], t1 = p[1], t2 = p[2];
  __shared__ float he[HID_], hp[HID_];
  int j = threadIdx.x;
  {
    float a = fmaf(t0, ew1[j], fmaf(t1, ew1[HID_ + j], fmaf(t2, ew1[2 * HID_ + j], eb1[j])));
    he[j] = fmaxf(a, 0.f);
    float c = fmaf(t0, pw1[j], fmaf(t1, pw1[HID_ + j], fmaf(t2, pw1[2 * HID_ + j], pb1[j])));
    hp[j] = fmaxf(c, 0.f);
  }
  __syncthreads();
  for (int d = j; d < D_; d += HID_) {
    float acc = eb2[d] + pb2[d];
    for (int k = 0; k < HID_; ++k) {
      acc = fmaf(he[k], ew2[k * D_ + d], acc);
      acc = fmaf(hp[k], pw2[k * D_ + d], acc);
    }
    x[(size_t)t * D_ + d] = acc;
  }
}

// ---------------- LayerNorm -> bf16, optional fused split-K combine + residual ----------------
__global__ __launch_bounds__(256) void ln_fused(
    const float* __restrict__ x, const float* __restrict__ pa,
    const float* __restrict__ pb, const float* __restrict__ bias,
    const float* __restrict__ s, const float* __restrict__ bb,
    float* __restrict__ xw, short* __restrict__ y16) {
  int r = blockIdx.x * 4 + (threadIdx.x >> 6);
  int t = threadIdx.x & 63;
  float4 v = ((const float4*)(x + (size_t)r * D_))[t];
  if (pa) {
    float4 a = ((const float4*)(pa + (size_t)r * D_))[t];
    float4 c = ((const float4*)(pb + (size_t)r * D_))[t];
    float4 bi = ((const float4*)bias)[t];
    v.x += a.x + c.x + bi.x;
    v.y += a.y + c.y + bi.y;
    v.z += a.z + c.z + bi.z;
    v.w += a.w + c.w + bi.w;
    ((float4*)(xw + (size_t)r * D_))[t] = v;
  }
  float sum = v.x + v.y + v.z + v.w;
  #pragma unroll
  for (int o = 1; o < 64; o <<= 1) sum += __shfl_xor(sum, o, 64);
  float mean = sum * (1.f / D_);
  float dx = v.x - mean, dy = v.y - mean, dz = v.z - mean, dw = v.w - mean;
  float vs = dx * dx + dy * dy + dz * dz + dw * dw;
  #pragma unroll
  for (int o = 1; o < 64; o <<= 1) vs += __shfl_xor(vs, o, 64);
  float inv = 1.0f / sqrtf(vs * (1.f / D_) + EPS_);
  float4 sv = ((const float4*)s)[t];
  float4 bv = ((const float4*)bb)[t];
  short4_t ov;
  ov[0] = f2bf(dx * inv * sv.x + bv.x);
  ov[1] = f2bf(dy * inv * sv.y + bv.y);
  ov[2] = f2bf(dz * inv * sv.z + bv.z);
  ov[3] = f2bf(dw * inv * sv.w + bv.w);
  *(short4_t*)(y16 + (size_t)r * D_ + t * 4) = ov;
}

// ---------------- head2: combine head1 partials + relu, one wave per token ----------------
__global__ __launch_bounds__(256) void head2_kernel(
    const float* __restrict__ pa, const float* __restrict__ pb,
    const float* __restrict__ b1h, const float* __restrict__ w2,
    const float* __restrict__ b2, float* __restrict__ lt) {
  __shared__ float ys[4][HHID_];
  int w = threadIdx.x >> 6, l = threadIdx.x & 63;
  int t = blockIdx.x * 4 + w;
  float4 a = ((const float4*)(pa + (size_t)t * HHID_))[l];
  float4 c = ((const float4*)(pb + (size_t)t * HHID_))[l];
  float4 bi = ((const float4*)b1h)[l];
  float4 v;
  v.x = fmaxf(a.x + c.x + bi.x, 0.f);
  v.y = fmaxf(a.y + c.y + bi.y, 0.f);
  v.z = fmaxf(a.z + c.z + bi.z, 0.f);
  v.w = fmaxf(a.w + c.w + bi.w, 0.f);
  *(float4*)&ys[w][l * 4] = v;
  int cc = l < C_ ? l : 0;
  float a0 = 0.f, a1 = 0.f, a2 = 0.f, a3 = 0.f;
  #pragma unroll 4
  for (int k = 0; k < HHID_; k += 4) {
    a0 = fmaf(ys[w][k + 0], w2[(k + 0) * C_ + cc], a0);
    a1 = fmaf(ys[w][k + 1], w2[(k + 1) * C_ + cc], a1);
    a2 = fmaf(ys[w][k + 2], w2[(k + 2) * C_ + cc], a2);
    a3 = fmaf(ys[w][k + 3], w2[(k + 3) * C_ + cc], a3);
  }
  if (l < C_) lt[(size_t)t * C_ + l] = (a0 + a1) + (a2 + a3) + b2[l];
}

// ---------------- all-bf16 MFMA GEMM: BM=64, BN=64, BK=32, global_load_lds staging ----------------
template <int ACT, int RES>
__device__ __forceinline__ void gemm16_body(
    const short* __restrict__ A16, const short* __restrict__ WT,
    const float* __restrict__ bias, const float* __restrict__ R,
    float* __restrict__ C, short* __restrict__ C16, short* __restrict__ VT,
    float oscale, int K, int Ncols, int m0, int n0) {
  __shared__ short As[64][32];
  __shared__ short Bs[64][32];
  int tid = threadIdx.x;
  int w = tid >> 6, l = tid & 63;
  int lq = l & 15, lg = l >> 4;
  int wr = (w & 1) * 32, wc = (w >> 1) * 32;
  int ga = (lg ^ (lq & 3)) * 8;
  f32x4 acc00 = {0.f, 0.f, 0.f, 0.f};
  f32x4 acc01 = {0.f, 0.f, 0.f, 0.f};
  f32x4 acc10 = {0.f, 0.f, 0.f, 0.f};
  f32x4 acc11 = {0.f, 0.f, 0.f, 0.f};
  for (int kk = 0; kk < K; kk += 32) {
    __syncthreads();
    stage16(A16 + (size_t)m0 * K + kk, &As[0][0], K, tid);
    stage16(WT + (size_t)n0 * K + kk, &Bs[0][0], K, tid);
    __syncthreads();
    short8 a0 = *(short8*)&As[wr + lq][ga];
    short8 a1 = *(short8*)&As[wr + 16 + lq][ga];
    short8 b0 = *(short8*)&Bs[wc + lq][ga];
    short8 b1 = *(short8*)&Bs[wc + 16 + lq][ga];
    acc00 = __builtin_amdgcn_mfma_f32_16x16x32_bf16(a0, b0, acc00, 0, 0, 0);
    acc01 = __builtin_amdgcn_mfma_f32_16x16x32_bf16(a0, b1, acc01, 0, 0, 0);
    acc10 = __builtin_amdgcn_mfma_f32_16x16x32_bf16(a1, b0, acc10, 0, 0, 0);
    acc11 = __builtin_amdgcn_mfma_f32_16x16x32_bf16(a1, b1, acc11, 0, 0, 0);
  }
  #pragma unroll
  for (int fi = 0; fi < 2; ++fi) {
    int row = m0 + wr + fi * 16 + lg * 4;
    #pragma unroll
    for (int fj = 0; fj < 2; ++fj) {
      int col = n0 + wc + fj * 16 + lq;
      short4_t vt4;
      #pragma unroll
      for (int r = 0; r < 4; ++r) {
        float v = (fi == 0 ? (fj == 0 ? acc00[r] : acc01[r])
                           : (fj == 0 ? acc10[r] : acc11[r])) + bias[col];
        if (ACT == 1) v = fmaxf(v, 0.f);
        else if (ACT == 2) v = 0.5f * v * (1.f + erff(v * 0.70710678118654752f));
        if (RES) v += R[(size_t)(row + r) * Ncols + col];
        if (C)   C[(size_t)(row + r) * Ncols + col] = v;
        if (C16) C16[(size_t)(row + r) * Ncols + col] = f2bf(v * oscale);
        if (VT)  vt4[r] = f2bf(v);
      }
      if (VT) {
        int bb = row >> 11, mm = row & (M_ - 1);
        *(short4_t*)&VT[((size_t)(bb * 256 + col)) * M_ + mm] = vt4;
      }
    }
  }
}

template <int ACT, int RES>
__global__ __launch_bounds__(256) void gemm16(
    const short* __restrict__ A16, const short* __restrict__ WT,
    const float* __restrict__ bias, const float* __restrict__ R,
    float* __restrict__ C, short* __restrict__ C16,
    int K, int Ncols) {
  gemm16_body<ACT, RES>(A16, WT, bias, R, C, C16, nullptr, 1.f, K, Ncols,
                        blockIdx.y * 64, blockIdx.x * 64);
}

// split-K partial GEMM
__global__ __launch_bounds__(256) void gemm16_part(
    const short* __restrict__ A16, const short* __restrict__ WT,
    float* __restrict__ P, int K, int Klen, int Ncols) {
  __shared__ short As[64][32];
  __shared__ short Bs[64][32];
  int tid = threadIdx.x;
  int w = tid >> 6, l = tid & 63;
  int lq = l & 15, lg = l >> 4;
  int wr = (w & 1) * 32, wc = (w >> 1) * 32;
  int ga = (lg ^ (lq & 3)) * 8;
  int m0 = blockIdx.y * 64, n0 = blockIdx.x * 64;
  int k0 = blockIdx.z * Klen;
  f32x4 acc00 = {0.f, 0.f, 0.f, 0.f};
  f32x4 acc01 = {0.f, 0.f, 0.f, 0.f};
  f32x4 acc10 = {0.f, 0.f, 0.f, 0.f};
  f32x4 acc11 = {0.f, 0.f, 0.f, 0.f};
  for (int kk = k0; kk < k0 + Klen; kk += 32) {
    __syncthreads();
    stage16(A16 + (size_t)m0 * K + kk, &As[0][0], K, tid);
    stage16(WT + (size_t)n0 * K + kk, &Bs[0][0], K, tid);
    __syncthreads();
    short8 a0 = *(short8*)&As[wr + lq][ga];
    short8 a1 = *(short8*)&As[wr + 16 + lq][ga];
    short8 b0 = *(short8*)&Bs[wc + lq][ga];
    short8 b1 = *(short8*)&Bs[wc + 16 + lq][ga];
    acc00 = __builtin_amdgcn_mfma_f32_16x16x32_bf16(a0, b0, acc00, 0, 0, 0);
    acc01 = __builtin_amdgcn_mfma_f32_16x16x32_bf16(a0, b1, acc01, 0, 0, 0);
    acc10 = __builtin_amdgcn_mfma_f32_16x16x32_bf16(a1, b0, acc10, 0, 0, 0);
    acc11 = __builtin_amdgcn_mfma_f32_16x16x32_bf16(a1, b1, acc11, 0, 0, 0);
  }
  float* Pp = P + (size_t)blockIdx.z * TOK_ * Ncols;
  #pragma unroll
  for (int fi = 0; fi < 2; ++fi) {
    int row = m0 + wr + fi * 16 + lg * 4;
    #pragma unroll
    for (int fj = 0; fj < 2; ++fj) {
      int col = n0 + wc + fj * 16 + lq;
      #pragma unroll
      for (int r = 0; r < 4; ++r) {
        float v = (fi == 0 ? (fj == 0 ? acc00[r] : acc01[r])
                           : (fj == 0 ? acc10[r] : acc11[r]));
        Pp[(size_t)(row + r) * Ncols + col] = v;
      }
    }
  }
}

// QKV: Q -> bf16 scaled by QSCALE_, K -> bf16, V -> bf16 transposed (direct)
__global__ __launch_bounds__(256) void qkv16(
    const short* __restrict__ A16,
    const short* __restrict__ WqT, const short* __restrict__ WkT, const short* __restrict__ WvT,
    const float* __restrict__ bq, const float* __restrict__ bk, const float* __restrict__ bv,
    short* __restrict__ q16, short* __restrict__ k16, short* __restrict__ vt16) {
  int sel = blockIdx.x >> 2;
  int n0 = (blockIdx.x & 3) << 6;
  int m0 = blockIdx.y * 64;
  if (sel == 0) {
    gemm16_body<0, 0>(A16, WqT, bq, nullptr, nullptr, q16, nullptr, QSCALE_, D_, D_, m0, n0);
  } else if (sel == 1) {
    gemm16_body<0, 0>(A16, WkT, bk, nullptr, nullptr, k16, nullptr, 1.f, D_, D_, m0, n0);
  } else {
    gemm16_body<0, 0>(A16, WvT, bv, nullptr, nullptr, nullptr, vt16, 1.f, D_, D_, m0, n0);
  }
}

// ---------------- Wo GEMM, split-K x2, fused attention combine (2 KV-halves) ----------------
__global__ __launch_bounds__(256) void wo_split(
    const float* __restrict__ po0, const float* __restrict__ po1,
    const float* __restrict__ pl, const short* __restrict__ WT,
    float* __restrict__ P) {
  __shared__ short As[64][136];
  __shared__ short Bs[64][32];
  int tid = threadIdx.x;
  int w = tid >> 6, l = tid & 63;
  int m0 = blockIdx.y * 64, n0 = blockIdx.x * 64;
  int half = blockIdx.z;
  int c2 = l * 2;
  int hh = half * 4 + (c2 >> 5);
  int d0 = c2 & 31;
  #pragma unroll 4
  for (int c = 0; c < 16; ++c) {
    int t = w * 16 + c;
    int row = m0 + t;
    int bb = row >> 11, mm = row & (M_ - 1);
    size_t f = (size_t)(bb * NHEAD_ + hh) * M_ + mm;
    float inv = 1.f / (pl[f] + pl[16 * M_ + f]);
    float v0 = (po0[f * 32 + d0] + po1[f * 32 + d0]) * inv;
    float v1 = (po0[f * 32 + d0 + 1] + po1[f * 32 + d0 + 1]) * inv;
    *(unsigned*)&As[t][c2] = cvt_pk_bf16(v0, v1);
  }
  int lq = l & 15, lg = l >> 4;
  int wr = (w & 1) * 32, wc = (w >> 1) * 32;
  int gb = (lg ^ (lq & 3)) * 8;
  f32x4 acc00 = {0.f, 0.f, 0.f, 0.f};
  f32x4 acc01 = {0.f, 0.f, 0.f, 0.f};
  f32x4 acc10 = {0.f, 0.f, 0.f, 0.f};
  f32x4 acc11 = {0.f, 0.f, 0.f, 0.f};
  for (int kk = 0; kk < 128; kk += 32) {
    __syncthreads();
    stage16(WT + (size_t)n0 * D_ + half * 128 + kk, &Bs[0][0], D_, tid);
    __syncthreads();
    short8 a0 = *(short8*)&As[wr + lq][kk + lg * 8];
    short8 a1 = *(short8*)&As[wr + 16 + lq][kk + lg * 8];
    short8 b0 = *(short8*)&Bs[wc + lq][gb];
    short8 b1 = *(short8*)&Bs[wc + 16 + lq][gb];
    acc00 = __builtin_amdgcn_mfma_f32_16x16x32_bf16(a0, b0, acc00, 0, 0, 0);
    acc01 = __builtin_amdgcn_mfma_f32_16x16x32_bf16(a0, b1, acc01, 0, 0, 0);
    acc10 = __builtin_amdgcn_mfma_f32_16x16x32_bf16(a1, b0, acc10, 0, 0, 0);
    acc11 = __builtin_amdgcn_mfma_f32_16x16x32_bf16(a1, b1, acc11, 0, 0, 0);
  }
  float* Pp = P + (size_t)half * TOK_ * D_;
  #pragma unroll
  for (int fi = 0; fi < 2; ++fi) {
    int row = m0 + wr + fi * 16 + lg * 4;
    #pragma unroll
    for (int fj = 0; fj < 2; ++fj) {
      int col = n0 + wc + fj * 16 + lq;
      #pragma unroll
      for (int r = 0; r < 4; ++r) {
        float v = (fi == 0 ? (fj == 0 ? acc00[r] : acc01[r])
                           : (fj == 0 ? acc10[r] : acc11[r]));
        Pp[(size_t)(row + r) * D_ + col] = v;
      }
    }
  }
}

// ---------------- flash attention: no-max exp2 softmax, KV-split x2, KVBLK=128 ----------------
// l computed via MFMA row-sum (ones-vector trick): no scalar adds, no shuffles.
__global__ __launch_bounds__(256) void attn_mfma_kernel(
    const short* __restrict__ q16, const short* __restrict__ k16,
    const short* __restrict__ vt16,
    float* __restrict__ po0, float* __restrict__ po1,
    float* __restrict__ pl) {
  __shared__ short Ks[128][40];
  __shared__ short Vt[32][136];
  __shared__ short Ps[4][16][136];
  int bid = blockIdx.x;
  int half = bid & 1;
  int qt = (bid >> 1) & 31;
  int h  = (bid >> 6) & 7;
  int b  = bid >> 9;
  int tid = threadIdx.x;
  int w  = tid >> 6;
  int l  = tid & 63;
  int lq = l & 15;
  int lg = l >> 4;

  short8 qf = *(const short8*)&q16[(size_t)(b * M_ + qt * 64 + w * 16 + lq) * D_ + h * DH_ + lg * 8];

  const short one = (short)0x3F80;   // bf16 1.0
  short8 ones = {one, one, one, one, one, one, one, one};

  f32x4 lacc = {0.f, 0.f, 0.f, 0.f};
  f32x4 o0 = {0.f, 0.f, 0.f, 0.f};
  f32x4 o1 = {0.f, 0.f, 0.f, 0.f};
  int srow = tid >> 1, scol = (tid & 1) * 16;
  int vd = tid >> 3, vm = (tid & 7) * 16;
  const short* kp = k16 + (size_t)(b * M_ + half * 1024 + srow) * D_ + h * DH_ + scol;
  const short* vp = vt16 + (size_t)((b * NHEAD_ + h) * DH_ + vd) * M_ + half * 1024 + vm;

  for (int kt = 0; kt < 8; ++kt) {
    __syncthreads();
    {
      const short* kg = kp + (size_t)(kt * 128) * D_;
      *(short8*)&Ks[srow][scol]     = *(const short8*)(kg);
      *(short8*)&Ks[srow][scol + 8] = *(const short8*)(kg + 8);
      const short* vg = vp + kt * 128;
      *(short8*)&Vt[vd][vm]     = *(const short8*)(vg);
      *(short8*)&Vt[vd][vm + 8] = *(const short8*)(vg + 8);
    }
    __syncthreads();
    f32x4 st[8];
    #pragma unroll
    for (int t = 0; t < 8; ++t) {
      short8 kf = *(short8*)&Ks[t * 16 + lq][lg * 8];
      f32x4 z = {0.f, 0.f, 0.f, 0.f};
      st[t] = __builtin_amdgcn_mfma_f32_16x16x32_bf16(kf, qf, z, 0, 0, 0);
    }
    #pragma unroll
    for (int t = 0; t < 8; ++t)
      #pragma unroll
      for (int r2 = 0; r2 < 4; ++r2)
        st[t][r2] = fast_exp2(st[t][r2]);
    {
      unsigned* pw = (unsigned*)&Ps[w][lq][0];
      #pragma unroll
      for (int t = 0; t < 8; ++t) {
        uint2 pk;
        pk.x = cvt_pk_bf16(st[t][0], st[t][1]);
        pk.y = cvt_pk_bf16(st[t][2], st[t][3]);
        *(uint2*)(pw + t * 8 + lg * 2) = pk;
      }
    }
    #pragma unroll
    for (int c = 0; c < 4; ++c) {
      short8 pf = *(short8*)&Ps[w][lq][c * 32 + lg * 8];
      short8 v0 = *(short8*)&Vt[lq][c * 32 + lg * 8];
      short8 v1 = *(short8*)&Vt[16 + lq][c * 32 + lg * 8];
      o0 = __builtin_amdgcn_mfma_f32_16x16x32_bf16(v0, pf, o0, 0, 0, 0);
      o1 = __builtin_amdgcn_mfma_f32_16x16x32_bf16(v1, pf, o1, 0, 0, 0);
      lacc = __builtin_amdgcn_mfma_f32_16x16x32_bf16(ones, pf, lacc, 0, 0, 0);
    }
  }
  int f = (b * NHEAD_ + h) * M_ + qt * 64 + w * 16 + lq;
  float* pp = (half == 0 ? po0 : po1) + (size_t)f * 32;
  #pragma unroll
  for (int r2 = 0; r2 < 4; ++r2) pp[lg * 4 + r2] = o0[r2];
  #pragma unroll
  for (int r2 = 0; r2 < 4; ++r2) pp[16 + lg * 4 + r2] = o1[r2];
  if (lg == 0) pl[half * (16 * M_) + f] = lacc[0];
}

// ---------------- KNN top-3 + gather/mean (proven R10/R14 version) ----------------
// 1024 blocks (512/batch), 512 threads, 32 queries/block, 16 lanes/query, chunk=128
__global__ __launch_bounds__(512) void knn_kernel(
    const float* __restrict__ xyz, const float* __restrict__ lt,
    float* __restrict__ out) {
  __shared__ float4 tok[2064];
  int b = blockIdx.x >> 9;
  int q0 = (blockIdx.x & 511) << 5;
  int tid = threadIdx.x;
  for (int i = tid; i < M_; i += 512) {
    const float* tp = xyz + ((size_t)b * N_ + (size_t)i * 8) * 3;
    float a = tp[0], bb = tp[1], cc = tp[2];
    tok[i + (i >> 7)] = make_float4(a, bb, cc, a * a + bb * bb + cc * cc);
  }
  __syncthreads();
  int g = tid >> 4, sl = tid & 15;
  int n = q0 + g;
  const float* qp = xyz + ((size_t)b * N_ + n) * 3;
  float qx = qp[0], qy = qp[1], qz = qp[2];
  float q2 = qx * qx + qy * qy + qz * qz;
  float dd0 = INFINITY, dd1 = INFINITY, dd2 = INFINITY;
  int ii0 = 0, ii1 = 0, ii2 = 0;
  const float4* cp = &tok[sl * 129];
  int mb = sl << 7;
  #pragma unroll 2
  for (int j = 0; j < 128; ++j) {
    float4 t = cp[j];
    float dot = fmaf(qx, t.x, fmaf(qy, t.y, qz * t.z));
    float d = fmaxf(q2 + t.w - 2.f * dot, 0.f);
    if (d < dd2) {
      int m = mb + j;
      if (d < dd1) {
        dd2 = dd1; ii2 = ii1;
        if (d < dd0) { dd1 = dd0; ii1 = ii0; dd0 = d; ii0 = m; }
        else         { dd1 = d;  ii1 = m; }
      } else         { dd2 = d;  ii2 = m; }
    }
  }
  auto insT = [&](float d, int i) {
    if (d < dd2 || (d == dd2 && i < ii2)) {
      if (d < dd1 || (d == dd1 && i < ii1)) {
        dd2 = dd1; ii2 = ii1;
        if (d < dd0 || (d == dd0 && i < ii0)) { dd1 = dd0; ii1 = ii0; dd0 = d; ii0 = i; }
        else { dd1 = d; ii1 = i; }
      } else { dd2 = d; ii2 = i; }
    }
  };
  #pragma unroll
  for (int off = 1; off < 16; off <<= 1) {
    float p0 = __shfl_xor(dd0, off, 64); int pi0 = __shfl_xor(ii0, off, 64);
    float p1 = __shfl_xor(dd1, off, 64); int pi1 = __shfl_xor(ii1, off, 64);
    float p2 = __shfl_xor(dd2, off, 64); int pi2 = __shfl_xor(ii2, off, 64);
    insT(p0, pi0); insT(p1, pi1); insT(p2, pi2);
  }
  const float* l0 = lt + ((size_t)b * M_ + ii0) * C_;
  const float* l1 = lt + ((size_t)b * M_ + ii1) * C_;
  const float* l2 = lt + ((size_t)b * M_ + ii2) * C_;
  float* op = out + ((size_t)b * N_ + n) * C_;
  for (int cc = sl; cc < C_; cc += 16)
    op[cc] = (l0[cc] + l1[cc] + l2[cc]) * (1.f / 3.f);
}

extern "C" void kernel_launch(void* const* d_in, const int* in_sizes, int n_in,
                              void* d_out, int out_size, void* d_ws, size_t ws_size,
                              hipStream_t stream) {
  const float* xyz  = (const float*)d_in[0];
  const float* ew1  = (const float*)d_in[1];
  const float* eb1  = (const float*)d_in[2];
  const float* ew2  = (const float*)d_in[3];
  const float* eb2  = (const float*)d_in[4];
  const float* pw1  = (const float*)d_in[5];
  const float* pb1  = (const float*)d_in[6];
  const float* pw2  = (const float*)d_in[7];
  const float* pb2  = (const float*)d_in[8];
  const float* Wq   = (const float*)d_in[9];
  const float* bq   = (const float*)d_in[10];
  const float* Wk   = (const float*)d_in[11];
  const float* bk   = (const float*)d_in[12];
  const float* Wv   = (const float*)d_in[13];
  const float* bv   = (const float*)d_in[14];
  const float* Wo   = (const float*)d_in[15];
  const float* bo   = (const float*)d_in[16];
  const float* ln1s = (const float*)d_in[17];
  const float* ln1b = (const float*)d_in[18];
  const float* W1   = (const float*)d_in[19];
  const float* b1   = (const float*)d_in[20];
  const float* W2   = (const float*)d_in[21];
  const float* b2   = (const float*)d_in[22];
  const float* ln2s = (const float*)d_in[23];
  const float* ln2b = (const float*)d_in[24];
  const float* hw1  = (const float*)d_in[25];
  const float* hb1  = (const float*)d_in[26];
  const float* hw2  = (const float*)d_in[27];
  const float* hb2  = (const float*)d_in[28];
  float* out = (float*)d_out;

  // ---- workspace layout ----
  float* x   = (float*)d_ws;
  float* y   = x + 1048576;
  float* po2 = y + 1048576;
  float* po3 = po2 + 1048576;
  float* lt  = po3 + 1048576;
  short* y16 = (short*)(lt + 204800);
  short* q16 = y16 + 1048576;
  short* k16 = q16 + 1048576;
  short* v16 = k16 + 1048576;
  short* vt16 = v16 + 1048576;
  short* ob16 = vt16 + 1048576;
  short* x16  = ob16 + 1048576;
  short* ff16 = x16 + 1048576;
  short* WqT = ff16 + 2097152;
  short* WkT = WqT + 262144;
  short* WvT = WkT + 262144;
  short* WoT = WvT + 262144;
  short* W1T = WoT + 262144;
  short* W2T = W1T + 524288;
  short* h1T = W2T + 524288;
  float* wpart = (float*)(h1T + 65536);
  float* po0 = y;
  float* po1 = (float*)ff16;
  float* pl  = lt;

  wconv_all<<<528, 256, 0, stream>>>(Wq, Wk, Wv, Wo, W1, W2, hw1,
                                     WqT, WkT, WvT, WoT, W1T, W2T, h1T);
  embed_kernel<<<TOK_, 128, 0, stream>>>(xyz, ew1, eb1, ew2, eb2, pw1, pb1, pw2, pb2, x);

  dim3 gQKV(12, TOK_ / 64);
  dim3 gDs(D_ / 64, TOK_ / 64, 2);
  dim3 gF(FF_ / 64, TOK_ / 64);
  dim3 gD(D_ / 64, TOK_ / 64);
  for (int l = 0; l < L_; ++l) {
    if (l == 0)
      ln_fused<<<TOK_ / 4, 256, 0, stream>>>(x, nullptr, nullptr, nullptr,
                                             ln1s + l * D_, ln1b + l * D_, x, y16);
    else
      ln_fused<<<TOK_ / 4, 256, 0, stream>>>(x, wpart, wpart + (size_t)TOK_ * D_,
                                             b2 + (l - 1) * D_,
                                             ln1s + l * D_, ln1b + l * D_, x, y16);
    qkv16<<<gQKV, 256, 0, stream>>>(y16, WqT + l * 65536, WkT + l * 65536, WvT + l * 65536,
                                    bq + l * D_, bk + l * D_, bv + l * D_, q16, k16, vt16);
    attn_mfma_kernel<<<1024, 256, 0, stream>>>(q16, k16, vt16, po0, po1, pl);
    wo_split<<<gDs, 256, 0, stream>>>(po0, po1, pl, WoT + l * 65536, wpart);
    ln_fused<<<TOK_ / 4, 256, 0, stream>>>(x, wpart, wpart + (size_t)TOK_ * D_,
                                           bo + l * D_,
                                           ln2s + l * D_, ln2b + l * D_, x, y16);
    gemm16<2, 0><<<gF, 256, 0, stream>>>(y16, W1T + l * 131072, b1 + l * FF_, nullptr, nullptr, ff16, D_, FF_);
    if (l < L_ - 1) {
      gemm16_part<<<gDs, 256, 0, stream>>>(ff16, W2T + l * 131072, wpart, FF_, 256, D_);
    } else {
      gemm16<0, 1><<<gD, 256, 0, stream>>>(ff16, W2T + l * 131072, b2 + l * D_, x, x, x16, FF_, D_);
    }
  }
  gemm16_part<<<gDs, 256, 0, stream>>>(x16, h1T, wpart, D_, 128, HHID_);
  head2_kernel<<<TOK_ / 4, 256, 0, stream>>>(wpart, wpart + (size_t)TOK_ * HHID_,
                                             hb1, hw2, hb2, lt);
  knn_kernel<<<1024, 512, 0, stream>>>(xyz, lt, out);
}

// Round 17
// 366.377 us; speedup vs baseline: 1.2197x; 1.0269x over previous
//
#include <hip/hip_runtime.h>
#include <hip/hip_bf16.h>
#include <math.h>

#define B_ 2
#define N_ 16384
#define M_ 2048
#define D_ 256
#define NHEAD_ 8
#define DH_ 32
#define FF_ 512
#define C_ 50
#define HID_ 128
#define HHID_ 256
#define L_ 4
#define EPS_ 1e-5f
#define TOK_ (B_*M_)   // 4096
#define QSCALE_ 0.25507604155757994f

typedef short short8 __attribute__((ext_vector_type(8)));
typedef short short4_t __attribute__((ext_vector_type(4)));
typedef float f32x4 __attribute__((ext_vector_type(4)));

__device__ __forceinline__ short f2bf(float f) {
  union { float f; unsigned u; } c; c.f = f;
  unsigned u = c.u;
  unsigned r = (u + 0x7FFFu + ((u >> 16) & 1u)) >> 16;
  return (short)r;
}
__device__ __forceinline__ float fast_exp2(float x) {
  float r;
  asm("v_exp_f32 %0, %1" : "=v"(r) : "v"(x));
  return r;
}
__device__ __forceinline__ unsigned cvt_pk_bf16(float lo, float hi) {
  unsigned r;
  asm("v_cvt_pk_bf16_f32 %0, %1, %2" : "=v"(r) : "v"(lo), "v"(hi));
  return r;
}

// async global->LDS stage of one 64x32-bf16 tile (4KB) by 256 threads.
__device__ __forceinline__ void stage16(const short* __restrict__ g, short* lds,
                                        int rowStride, int tid) {
  int row = tid >> 2, gr = tid & 3;
  int kg = gr ^ (row & 3);
  __builtin_amdgcn_global_load_lds(
      (const __attribute__((address_space(1))) void*)(g + (size_t)row * rowStride + kg * 8),
      (__attribute__((address_space(3))) void*)(lds + tid * 8),
      16, 0, 0);
}

// ---------------- one-time weight convert + transpose to bf16 [N][K] ----------------
__global__ __launch_bounds__(256) void wconv_all(
    const float* __restrict__ Wq, const float* __restrict__ Wk,
    const float* __restrict__ Wv, const float* __restrict__ Wo,
    const float* __restrict__ W1, const float* __restrict__ W2,
    const float* __restrict__ h1,
    short* __restrict__ WqT, short* __restrict__ WkT,
    short* __restrict__ WvT, short* __restrict__ WoT,
    short* __restrict__ W1T, short* __restrict__ W2T, short* __restrict__ h1T) {
  int bid = blockIdx.x;
  const float* W; short* WT; int Kd, Nd, tn, tk;
  if (bid < 256) {
    int mat = bid >> 6, rem = bid & 63, l = rem >> 4, t = rem & 15;
    W  = (mat == 0 ? Wq : mat == 1 ? Wk : mat == 2 ? Wv : Wo) + l * 65536;
    WT = (mat == 0 ? WqT : mat == 1 ? WkT : mat == 2 ? WvT : WoT) + l * 65536;
    Kd = 256; Nd = 256; tn = t & 3; tk = t >> 2;
  } else if (bid < 384) {
    int rem = bid - 256, l = rem >> 5, t = rem & 31;
    W = W1 + l * 131072; WT = W1T + l * 131072;
    Kd = 256; Nd = 512; tn = t & 7; tk = t >> 3;
  } else if (bid < 512) {
    int rem = bid - 384, l = rem >> 5, t = rem & 31;
    W = W2 + l * 131072; WT = W2T + l * 131072;
    Kd = 512; Nd = 256; tn = t & 3; tk = t >> 2;
  } else {
    int t = bid - 512;
    W = h1; WT = h1T; Kd = 256; Nd = 256; tn = t & 3; tk = t >> 2;
  }
  int n0 = tn * 64, k0 = tk * 64;
  __shared__ short ts[64][72];
  int tid = threadIdx.x;
  #pragma unroll
  for (int i = 0; i < 4; ++i) {
    int r = i * 16 + (tid >> 4);
    int c4 = (tid & 15) * 4;
    float4 v = *(const float4*)&W[(size_t)(k0 + r) * Nd + n0 + c4];
    ts[c4 + 0][r] = f2bf(v.x);
    ts[c4 + 1][r] = f2bf(v.y);
    ts[c4 + 2][r] = f2bf(v.z);
    ts[c4 + 3][r] = f2bf(v.w);
  }
  __syncthreads();
  #pragma unroll
  for (int i = 0; i < 2; ++i) {
    int n = i * 32 + (tid >> 3);
    int kc = (tid & 7) * 8;
    *(short8*)&WT[(size_t)(n0 + n) * Kd + k0 + kc] = *(short8*)&ts[n][kc];
  }
}

// ---------------- fused embed + pos MLP ----------------
__global__ __launch_bounds__(128) void embed_kernel(
    const float* __restrict__ xyz,
    const float* __restrict__ ew1, const float* __restrict__ eb1,
    const float* __restrict__ ew2, const float* __restrict__ eb2,
    const float* __restrict__ pw1, const float* __restrict__ pb1,
    const float* __restrict__ pw2, const float* __restrict__ pb2,
    float* __restrict__ x) {
  int t = blockIdx.x;
  int b = t / M_, m = t % M_;
  const float* p = xyz + ((size_t)b * N_ + (size_t)m * 8) * 3;
  float t0 = p[0], t1 = p[1], t2 = p[2];
  __shared__ float he[HID_], hp[HID_];
  int j = threadIdx.x;
  {
    float a = fmaf(t0, ew1[j], fmaf(t1, ew1[HID_ + j], fmaf(t2, ew1[2 * HID_ + j], eb1[j])));
    he[j] = fmaxf(a, 0.f);
    float c = fmaf(t0, pw1[j], fmaf(t1, pw1[HID_ + j], fmaf(t2, pw1[2 * HID_ + j], pb1[j])));
    hp[j] = fmaxf(c, 0.f);
  }
  __syncthreads();
  for (int d = j; d < D_; d += HID_) {
    float acc = eb2[d] + pb2[d];
    for (int k = 0; k < HID_; ++k) {
      acc = fmaf(he[k], ew2[k * D_ + d], acc);
      acc = fmaf(hp[k], pw2[k * D_ + d], acc);
    }
    x[(size_t)t * D_ + d] = acc;
  }
}

// ---------------- LayerNorm -> bf16, optional fused split-K combine + residual ----------------
__global__ __launch_bounds__(256) void ln_fused(
    const float* __restrict__ x, const float* __restrict__ pa,
    const float* __restrict__ pb, const float* __restrict__ bias,
    const float* __restrict__ s, const float* __restrict__ bb,
    float* __restrict__ xw, short* __restrict__ y16) {
  int r = blockIdx.x * 4 + (threadIdx.x >> 6);
  int t = threadIdx.x & 63;
  float4 v = ((const float4*)(x + (size_t)r * D_))[t];
  if (pa) {
    float4 a = ((const float4*)(pa + (size_t)r * D_))[t];
    float4 c = ((const float4*)(pb + (size_t)r * D_))[t];
    float4 bi = ((const float4*)bias)[t];
    v.x += a.x + c.x + bi.x;
    v.y += a.y + c.y + bi.y;
    v.z += a.z + c.z + bi.z;
    v.w += a.w + c.w + bi.w;
    ((float4*)(xw + (size_t)r * D_))[t] = v;
  }
  float sum = v.x + v.y + v.z + v.w;
  #pragma unroll
  for (int o = 1; o < 64; o <<= 1) sum += __shfl_xor(sum, o, 64);
  float mean = sum * (1.f / D_);
  float dx = v.x - mean, dy = v.y - mean, dz = v.z - mean, dw = v.w - mean;
  float vs = dx * dx + dy * dy + dz * dz + dw * dw;
  #pragma unroll
  for (int o = 1; o < 64; o <<= 1) vs += __shfl_xor(vs, o, 64);
  float inv = 1.0f / sqrtf(vs * (1.f / D_) + EPS_);
  float4 sv = ((const float4*)s)[t];
  float4 bv = ((const float4*)bb)[t];
  short4_t ov;
  ov[0] = f2bf(dx * inv * sv.x + bv.x);
  ov[1] = f2bf(dy * inv * sv.y + bv.y);
  ov[2] = f2bf(dz * inv * sv.z + bv.z);
  ov[3] = f2bf(dw * inv * sv.w + bv.w);
  *(short4_t*)(y16 + (size_t)r * D_ + t * 4) = ov;
}

// ---------------- head2: combine head1 partials + relu, one wave per token ----------------
__global__ __launch_bounds__(256) void head2_kernel(
    const float* __restrict__ pa, const float* __restrict__ pb,
    const float* __restrict__ b1h, const float* __restrict__ w2,
    const float* __restrict__ b2, float* __restrict__ lt) {
  __shared__ float ys[4][HHID_];
  int w = threadIdx.x >> 6, l = threadIdx.x & 63;
  int t = blockIdx.x * 4 + w;
  float4 a = ((const float4*)(pa + (size_t)t * HHID_))[l];
  float4 c = ((const float4*)(pb + (size_t)t * HHID_))[l];
  float4 bi = ((const float4*)b1h)[l];
  float4 v;
  v.x = fmaxf(a.x + c.x + bi.x, 0.f);
  v.y = fmaxf(a.y + c.y + bi.y, 0.f);
  v.z = fmaxf(a.z + c.z + bi.z, 0.f);
  v.w = fmaxf(a.w + c.w + bi.w, 0.f);
  *(float4*)&ys[w][l * 4] = v;
  int cc = l < C_ ? l : 0;
  float a0 = 0.f, a1 = 0.f, a2 = 0.f, a3 = 0.f;
  #pragma unroll 4
  for (int k = 0; k < HHID_; k += 4) {
    a0 = fmaf(ys[w][k + 0], w2[(k + 0) * C_ + cc], a0);
    a1 = fmaf(ys[w][k + 1], w2[(k + 1) * C_ + cc], a1);
    a2 = fmaf(ys[w][k + 2], w2[(k + 2) * C_ + cc], a2);
    a3 = fmaf(ys[w][k + 3], w2[(k + 3) * C_ + cc], a3);
  }
  if (l < C_) lt[(size_t)t * C_ + l] = (a0 + a1) + (a2 + a3) + b2[l];
}

// ---------------- all-bf16 MFMA GEMM: BM=64, BN=64, BK=32, global_load_lds staging ----------------
template <int ACT, int RES>
__device__ __forceinline__ void gemm16_body(
    const short* __restrict__ A16, const short* __restrict__ WT,
    const float* __restrict__ bias, const float* __restrict__ R,
    float* __restrict__ C, short* __restrict__ C16, short* __restrict__ VT,
    float oscale, int K, int Ncols, int m0, int n0) {
  __shared__ short As[64][32];
  __shared__ short Bs[64][32];
  int tid = threadIdx.x;
  int w = tid >> 6, l = tid & 63;
  int lq = l & 15, lg = l >> 4;
  int wr = (w & 1) * 32, wc = (w >> 1) * 32;
  int ga = (lg ^ (lq & 3)) * 8;
  f32x4 acc00 = {0.f, 0.f, 0.f, 0.f};
  f32x4 acc01 = {0.f, 0.f, 0.f, 0.f};
  f32x4 acc10 = {0.f, 0.f, 0.f, 0.f};
  f32x4 acc11 = {0.f, 0.f, 0.f, 0.f};
  for (int kk = 0; kk < K; kk += 32) {
    __syncthreads();
    stage16(A16 + (size_t)m0 * K + kk, &As[0][0], K, tid);
    stage16(WT + (size_t)n0 * K + kk, &Bs[0][0], K, tid);
    __syncthreads();
    short8 a0 = *(short8*)&As[wr + lq][ga];
    short8 a1 = *(short8*)&As[wr + 16 + lq][ga];
    short8 b0 = *(short8*)&Bs[wc + lq][ga];
    short8 b1 = *(short8*)&Bs[wc + 16 + lq][ga];
    acc00 = __builtin_amdgcn_mfma_f32_16x16x32_bf16(a0, b0, acc00, 0, 0, 0);
    acc01 = __builtin_amdgcn_mfma_f32_16x16x32_bf16(a0, b1, acc01, 0, 0, 0);
    acc10 = __builtin_amdgcn_mfma_f32_16x16x32_bf16(a1, b0, acc10, 0, 0, 0);
    acc11 = __builtin_amdgcn_mfma_f32_16x16x32_bf16(a1, b1, acc11, 0, 0, 0);
  }
  #pragma unroll
  for (int fi = 0; fi < 2; ++fi) {
    int row = m0 + wr + fi * 16 + lg * 4;
    #pragma unroll
    for (int fj = 0; fj < 2; ++fj) {
      int col = n0 + wc + fj * 16 + lq;
      short4_t vt4;
      #pragma unroll
      for (int r = 0; r < 4; ++r) {
        float v = (fi == 0 ? (fj == 0 ? acc00[r] : acc01[r])
                           : (fj == 0 ? acc10[r] : acc11[r])) + bias[col];
        if (ACT == 1) v = fmaxf(v, 0.f);
        else if (ACT == 2) v = 0.5f * v * (1.f + erff(v * 0.70710678118654752f));
        if (RES) v += R[(size_t)(row + r) * Ncols + col];
        if (C)   C[(size_t)(row + r) * Ncols + col] = v;
        if (C16) C16[(size_t)(row + r) * Ncols + col] = f2bf(v * oscale);
        if (VT)  vt4[r] = f2bf(v);
      }
      if (VT) {
        int bb = row >> 11, mm = row & (M_ - 1);
        *(short4_t*)&VT[((size_t)(bb * 256 + col)) * M_ + mm] = vt4;
      }
    }
  }
}

template <int ACT, int RES>
__global__ __launch_bounds__(256) void gemm16(
    const short* __restrict__ A16, const short* __restrict__ WT,
    const float* __restrict__ bias, const float* __restrict__ R,
    float* __restrict__ C, short* __restrict__ C16,
    int K, int Ncols) {
  gemm16_body<ACT, RES>(A16, WT, bias, R, C, C16, nullptr, 1.f, K, Ncols,
                        blockIdx.y * 64, blockIdx.x * 64);
}

// split-K partial GEMM
__global__ __launch_bounds__(256) void gemm16_part(
    const short* __restrict__ A16, const short* __restrict__ WT,
    float* __restrict__ P, int K, int Klen, int Ncols) {
  __shared__ short As[64][32];
  __shared__ short Bs[64][32];
  int tid = threadIdx.x;
  int w = tid >> 6, l = tid & 63;
  int lq = l & 15, lg = l >> 4;
  int wr = (w & 1) * 32, wc = (w >> 1) * 32;
  int ga = (lg ^ (lq & 3)) * 8;
  int m0 = blockIdx.y * 64, n0 = blockIdx.x * 64;
  int k0 = blockIdx.z * Klen;
  f32x4 acc00 = {0.f, 0.f, 0.f, 0.f};
  f32x4 acc01 = {0.f, 0.f, 0.f, 0.f};
  f32x4 acc10 = {0.f, 0.f, 0.f, 0.f};
  f32x4 acc11 = {0.f, 0.f, 0.f, 0.f};
  for (int kk = k0; kk < k0 + Klen; kk += 32) {
    __syncthreads();
    stage16(A16 + (size_t)m0 * K + kk, &As[0][0], K, tid);
    stage16(WT + (size_t)n0 * K + kk, &Bs[0][0], K, tid);
    __syncthreads();
    short8 a0 = *(short8*)&As[wr + lq][ga];
    short8 a1 = *(short8*)&As[wr + 16 + lq][ga];
    short8 b0 = *(short8*)&Bs[wc + lq][ga];
    short8 b1 = *(short8*)&Bs[wc + 16 + lq][ga];
    acc00 = __builtin_amdgcn_mfma_f32_16x16x32_bf16(a0, b0, acc00, 0, 0, 0);
    acc01 = __builtin_amdgcn_mfma_f32_16x16x32_bf16(a0, b1, acc01, 0, 0, 0);
    acc10 = __builtin_amdgcn_mfma_f32_16x16x32_bf16(a1, b0, acc10, 0, 0, 0);
    acc11 = __builtin_amdgcn_mfma_f32_16x16x32_bf16(a1, b1, acc11, 0, 0, 0);
  }
  float* Pp = P + (size_t)blockIdx.z * TOK_ * Ncols;
  #pragma unroll
  for (int fi = 0; fi < 2; ++fi) {
    int row = m0 + wr + fi * 16 + lg * 4;
    #pragma unroll
    for (int fj = 0; fj < 2; ++fj) {
      int col = n0 + wc + fj * 16 + lq;
      #pragma unroll
      for (int r = 0; r < 4; ++r) {
        float v = (fi == 0 ? (fj == 0 ? acc00[r] : acc01[r])
                           : (fj == 0 ? acc10[r] : acc11[r]));
        Pp[(size_t)(row + r) * Ncols + col] = v;
      }
    }
  }
}

// QKV: Q -> bf16 scaled by QSCALE_, K -> bf16, V -> bf16 transposed (direct)
__global__ __launch_bounds__(256) void qkv16(
    const short* __restrict__ A16,
    const short* __restrict__ WqT, const short* __restrict__ WkT, const short* __restrict__ WvT,
    const float* __restrict__ bq, const float* __restrict__ bk, const float* __restrict__ bv,
    short* __restrict__ q16, short* __restrict__ k16, short* __restrict__ vt16) {
  int sel = blockIdx.x >> 2;
  int n0 = (blockIdx.x & 3) << 6;
  int m0 = blockIdx.y * 64;
  if (sel == 0) {
    gemm16_body<0, 0>(A16, WqT, bq, nullptr, nullptr, q16, nullptr, QSCALE_, D_, D_, m0, n0);
  } else if (sel == 1) {
    gemm16_body<0, 0>(A16, WkT, bk, nullptr, nullptr, k16, nullptr, 1.f, D_, D_, m0, n0);
  } else {
    gemm16_body<0, 0>(A16, WvT, bv, nullptr, nullptr, nullptr, vt16, 1.f, D_, D_, m0, n0);
  }
}

// ---------------- Wo GEMM, split-K x2, fused attention combine (2 KV-halves) ----------------
__global__ __launch_bounds__(256) void wo_split(
    const float* __restrict__ po0, const float* __restrict__ po1,
    const float* __restrict__ pl, const short* __restrict__ WT,
    float* __restrict__ P) {
  __shared__ short As[64][136];
  __shared__ short Bs[64][32];
  int tid = threadIdx.x;
  int w = tid >> 6, l = tid & 63;
  int m0 = blockIdx.y * 64, n0 = blockIdx.x * 64;
  int half = blockIdx.z;
  int c2 = l * 2;
  int hh = half * 4 + (c2 >> 5);
  int d0 = c2 & 31;
  #pragma unroll 4
  for (int c = 0; c < 16; ++c) {
    int t = w * 16 + c;
    int row = m0 + t;
    int bb = row >> 11, mm = row & (M_ - 1);
    size_t f = (size_t)(bb * NHEAD_ + hh) * M_ + mm;
    float inv = 1.f / (pl[f] + pl[16 * M_ + f]);
    float v0 = (po0[f * 32 + d0] + po1[f * 32 + d0]) * inv;
    float v1 = (po0[f * 32 + d0 + 1] + po1[f * 32 + d0 + 1]) * inv;
    *(unsigned*)&As[t][c2] = cvt_pk_bf16(v0, v1);
  }
  int lq = l & 15, lg = l >> 4;
  int wr = (w & 1) * 32, wc = (w >> 1) * 32;
  int gb = (lg ^ (lq & 3)) * 8;
  f32x4 acc00 = {0.f, 0.f, 0.f, 0.f};
  f32x4 acc01 = {0.f, 0.f, 0.f, 0.f};
  f32x4 acc10 = {0.f, 0.f, 0.f, 0.f};
  f32x4 acc11 = {0.f, 0.f, 0.f, 0.f};
  for (int kk = 0; kk < 128; kk += 32) {
    __syncthreads();
    stage16(WT + (size_t)n0 * D_ + half * 128 + kk, &Bs[0][0], D_, tid);
    __syncthreads();
    short8 a0 = *(short8*)&As[wr + lq][kk + lg * 8];
    short8 a1 = *(short8*)&As[wr + 16 + lq][kk + lg * 8];
    short8 b0 = *(short8*)&Bs[wc + lq][gb];
    short8 b1 = *(short8*)&Bs[wc + 16 + lq][gb];
    acc00 = __builtin_amdgcn_mfma_f32_16x16x32_bf16(a0, b0, acc00, 0, 0, 0);
    acc01 = __builtin_amdgcn_mfma_f32_16x16x32_bf16(a0, b1, acc01, 0, 0, 0);
    acc10 = __builtin_amdgcn_mfma_f32_16x16x32_bf16(a1, b0, acc10, 0, 0, 0);
    acc11 = __builtin_amdgcn_mfma_f32_16x16x32_bf16(a1, b1, acc11, 0, 0, 0);
  }
  float* Pp = P + (size_t)half * TOK_ * D_;
  #pragma unroll
  for (int fi = 0; fi < 2; ++fi) {
    int row = m0 + wr + fi * 16 + lg * 4;
    #pragma unroll
    for (int fj = 0; fj < 2; ++fj) {
      int col = n0 + wc + fj * 16 + lq;
      #pragma unroll
      for (int r = 0; r < 4; ++r) {
        float v = (fi == 0 ? (fj == 0 ? acc00[r] : acc01[r])
                           : (fj == 0 ? acc10[r] : acc11[r]));
        Pp[(size_t)(row + r) * D_ + col] = v;
      }
    }
  }
}

// ---------------- flash attention: no-max exp2, KV-split x2, KVBLK=128 ----------------
// reg double-buffered staging (loads overlap compute), Ps halved (2-phase reuse)
__global__ __launch_bounds__(256) void attn_mfma_kernel(
    const short* __restrict__ q16, const short* __restrict__ k16,
    const short* __restrict__ vt16,
    float* __restrict__ po0, float* __restrict__ po1,
    float* __restrict__ pl) {
  __shared__ short Ks[128][40];      // 10.2 KB
  __shared__ short Vt[32][136];      // 8.7 KB
  __shared__ short Ps[4][16][72];    // 9.2 KB (half-P, reused)
  int bid = blockIdx.x;
  int half = bid & 1;
  int qt = (bid >> 1) & 31;
  int h  = (bid >> 6) & 7;
  int b  = bid >> 9;
  int tid = threadIdx.x;
  int w  = tid >> 6;
  int l  = tid & 63;
  int lq = l & 15;
  int lg = l >> 4;

  short8 qf = *(const short8*)&q16[(size_t)(b * M_ + qt * 64 + w * 16 + lq) * D_ + h * DH_ + lg * 8];

  const short one = (short)0x3F80;   // bf16 1.0
  short8 ones = {one, one, one, one, one, one, one, one};

  f32x4 lacc = {0.f, 0.f, 0.f, 0.f};
  f32x4 o0 = {0.f, 0.f, 0.f, 0.f};
  f32x4 o1 = {0.f, 0.f, 0.f, 0.f};
  int srow = tid >> 1, scol = (tid & 1) * 16;
  int vd = tid >> 3, vm = (tid & 7) * 16;
  const short* kp = k16 + (size_t)(b * M_ + half * 1024 + srow) * D_ + h * DH_ + scol;
  const short* vp = vt16 + (size_t)((b * NHEAD_ + h) * DH_ + vd) * M_ + half * 1024 + vm;

  // prologue: load tile 0 into regs
  short8 ka0 = *(const short8*)(kp);
  short8 ka1 = *(const short8*)(kp + 8);
  short8 va0 = *(const short8*)(vp);
  short8 va1 = *(const short8*)(vp + 8);

  for (int kt = 0; kt < 8; ++kt) {
    __syncthreads();
    *(short8*)&Ks[srow][scol]     = ka0;
    *(short8*)&Ks[srow][scol + 8] = ka1;
    *(short8*)&Vt[vd][vm]         = va0;
    *(short8*)&Vt[vd][vm + 8]     = va1;
    // issue next-tile loads: latency hides under this iteration's compute
    short8 nk0, nk1, nv0, nv1;
    if (kt < 7) {
      const short* kg = kp + (size_t)((kt + 1) * 128) * D_;
      nk0 = *(const short8*)(kg);
      nk1 = *(const short8*)(kg + 8);
      const short* vg = vp + (kt + 1) * 128;
      nv0 = *(const short8*)(vg);
      nv1 = *(const short8*)(vg + 8);
    }
    __syncthreads();
    f32x4 st[8];
    #pragma unroll
    for (int t = 0; t < 8; ++t) {
      short8 kf = *(short8*)&Ks[t * 16 + lq][lg * 8];
      f32x4 z = {0.f, 0.f, 0.f, 0.f};
      st[t] = __builtin_amdgcn_mfma_f32_16x16x32_bf16(kf, qf, z, 0, 0, 0);
    }
    #pragma unroll
    for (int t = 0; t < 8; ++t)
      #pragma unroll
      for (int r2 = 0; r2 < 4; ++r2)
        st[t][r2] = fast_exp2(st[t][r2]);
    unsigned* pw = (unsigned*)&Ps[w][lq][0];
    // P half 0: kv 0..63 (t=0..3), then PV c=0,1 (wave-synchronous LDS reuse)
    #pragma unroll
    for (int t = 0; t < 4; ++t) {
      uint2 pk;
      pk.x = cvt_pk_bf16(st[t][0], st[t][1]);
      pk.y = cvt_pk_bf16(st[t][2], st[t][3]);
      *(uint2*)(pw + t * 8 + lg * 2) = pk;
    }
    #pragma unroll
    for (int c = 0; c < 2; ++c) {
      short8 pf = *(short8*)&Ps[w][lq][c * 32 + lg * 8];
      short8 v0 = *(short8*)&Vt[lq][c * 32 + lg * 8];
      short8 v1 = *(short8*)&Vt[16 + lq][c * 32 + lg * 8];
      o0 = __builtin_amdgcn_mfma_f32_16x16x32_bf16(v0, pf, o0, 0, 0, 0);
      o1 = __builtin_amdgcn_mfma_f32_16x16x32_bf16(v1, pf, o1, 0, 0, 0);
      lacc = __builtin_amdgcn_mfma_f32_16x16x32_bf16(ones, pf, lacc, 0, 0, 0);
    }
    // P half 1: kv 64..127 (t=4..7) into same buffer, then PV c=2,3
    #pragma unroll
    for (int t = 4; t < 8; ++t) {
      uint2 pk;
      pk.x = cvt_pk_bf16(st[t][0], st[t][1]);
      pk.y = cvt_pk_bf16(st[t][2], st[t][3]);
      *(uint2*)(pw + (t - 4) * 8 + lg * 2) = pk;
    }
    #pragma unroll
    for (int c = 2; c < 4; ++c) {
      short8 pf = *(short8*)&Ps[w][lq][(c - 2) * 32 + lg * 8];
      short8 v0 = *(short8*)&Vt[lq][c * 32 + lg * 8];
      short8 v1 = *(short8*)&Vt[16 + lq][c * 32 + lg * 8];
      o0 = __builtin_amdgcn_mfma_f32_16x16x32_bf16(v0, pf, o0, 0, 0, 0);
      o1 = __builtin_amdgcn_mfma_f32_16x16x32_bf16(v1, pf, o1, 0, 0, 0);
      lacc = __builtin_amdgcn_mfma_f32_16x16x32_bf16(ones, pf, lacc, 0, 0, 0);
    }
    ka0 = nk0; ka1 = nk1; va0 = nv0; va1 = nv1;
  }
  int f = (b * NHEAD_ + h) * M_ + qt * 64 + w * 16 + lq;
  float* pp = (half == 0 ? po0 : po1) + (size_t)f * 32;
  #pragma unroll
  for (int r2 = 0; r2 < 4; ++r2) pp[lg * 4 + r2] = o0[r2];
  #pragma unroll
  for (int r2 = 0; r2 < 4; ++r2) pp[16 + lg * 4 + r2] = o1[r2];
  if (lg == 0) pl[half * (16 * M_) + f] = lacc[0];
}

// ---------------- KNN top-3 + gather/mean (proven R10/R14 version) ----------------
__global__ __launch_bounds__(512) void knn_kernel(
    const float* __restrict__ xyz, const float* __restrict__ lt,
    float* __restrict__ out) {
  __shared__ float4 tok[2064];
  int b = blockIdx.x >> 9;
  int q0 = (blockIdx.x & 511) << 5;
  int tid = threadIdx.x;
  for (int i = tid; i < M_; i += 512) {
    const float* tp = xyz + ((size_t)b * N_ + (size_t)i * 8) * 3;
    float a = tp[0], bb = tp[1], cc = tp[2];
    tok[i + (i >> 7)] = make_float4(a, bb, cc, a * a + bb * bb + cc * cc);
  }
  __syncthreads();
  int g = tid >> 4, sl = tid & 15;
  int n = q0 + g;
  const float* qp = xyz + ((size_t)b * N_ + n) * 3;
  float qx = qp[0], qy = qp[1], qz = qp[2];
  float q2 = qx * qx + qy * qy + qz * qz;
  float dd0 = INFINITY, dd1 = INFINITY, dd2 = INFINITY;
  int ii0 = 0, ii1 = 0, ii2 = 0;
  const float4* cp = &tok[sl * 129];
  int mb = sl << 7;
  #pragma unroll 2
  for (int j = 0; j < 128; ++j) {
    float4 t = cp[j];
    float dot = fmaf(qx, t.x, fmaf(qy, t.y, qz * t.z));
    float d = fmaxf(q2 + t.w - 2.f * dot, 0.f);
    if (d < dd2) {
      int m = mb + j;
      if (d < dd1) {
        dd2 = dd1; ii2 = ii1;
        if (d < dd0) { dd1 = dd0; ii1 = ii0; dd0 = d; ii0 = m; }
        else         { dd1 = d;  ii1 = m; }
      } else         { dd2 = d;  ii2 = m; }
    }
  }
  auto insT = [&](float d, int i) {
    if (d < dd2 || (d == dd2 && i < ii2)) {
      if (d < dd1 || (d == dd1 && i < ii1)) {
        dd2 = dd1; ii2 = ii1;
        if (d < dd0 || (d == dd0 && i < ii0)) { dd1 = dd0; ii1 = ii0; dd0 = d; ii0 = i; }
        else { dd1 = d; ii1 = i; }
      } else { dd2 = d; ii2 = i; }
    }
  };
  #pragma unroll
  for (int off = 1; off < 16; off <<= 1) {
    float p0 = __shfl_xor(dd0, off, 64); int pi0 = __shfl_xor(ii0, off, 64);
    float p1 = __shfl_xor(dd1, off, 64); int pi1 = __shfl_xor(ii1, off, 64);
    float p2 = __shfl_xor(dd2, off, 64); int pi2 = __shfl_xor(ii2, off, 64);
    insT(p0, pi0); insT(p1, pi1); insT(p2, pi2);
  }
  const float* l0 = lt + ((size_t)b * M_ + ii0) * C_;
  const float* l1 = lt + ((size_t)b * M_ + ii1) * C_;
  const float* l2 = lt + ((size_t)b * M_ + ii2) * C_;
  float* op = out + ((size_t)b * N_ + n) * C_;
  for (int cc = sl; cc < C_; cc += 16)
    op[cc] = (l0[cc] + l1[cc] + l2[cc]) * (1.f / 3.f);
}

extern "C" void kernel_launch(void* const* d_in, const int* in_sizes, int n_in,
                              void* d_out, int out_size, void* d_ws, size_t ws_size,
                              hipStream_t stream) {
  const float* xyz  = (const float*)d_in[0];
  const float* ew1  = (const float*)d_in[1];
  const float* eb1  = (const float*)d_in[2];
  const float* ew2  = (const float*)d_in[3];
  const float* eb2  = (const float*)d_in[4];
  const float* pw1  = (const float*)d_in[5];
  const float* pb1  = (const float*)d_in[6];
  const float* pw2  = (const float*)d_in[7];
  const float* pb2  = (const float*)d_in[8];
  const float* Wq   = (const float*)d_in[9];
  const float* bq   = (const float*)d_in[10];
  const float* Wk   = (const float*)d_in[11];
  const float* bk   = (const float*)d_in[12];
  const float* Wv   = (const float*)d_in[13];
  const float* bv   = (const float*)d_in[14];
  const float* Wo   = (const float*)d_in[15];
  const float* bo   = (const float*)d_in[16];
  const float* ln1s = (const float*)d_in[17];
  const float* ln1b = (const float*)d_in[18];
  const float* W1   = (const float*)d_in[19];
  const float* b1   = (const float*)d_in[20];
  const float* W2   = (const float*)d_in[21];
  const float* b2   = (const float*)d_in[22];
  const float* ln2s = (const float*)d_in[23];
  const float* ln2b = (const float*)d_in[24];
  const float* hw1  = (const float*)d_in[25];
  const float* hb1  = (const float*)d_in[26];
  const float* hw2  = (const float*)d_in[27];
  const float* hb2  = (const float*)d_in[28];
  float* out = (float*)d_out;

  // ---- workspace layout ----
  float* x   = (float*)d_ws;
  float* y   = x + 1048576;
  float* po2 = y + 1048576;
  float* po3 = po2 + 1048576;
  float* lt  = po3 + 1048576;
  short* y16 = (short*)(lt + 204800);
  short* q16 = y16 + 1048576;
  short* k16 = q16 + 1048576;
  short* v16 = k16 + 1048576;
  short* vt16 = v16 + 1048576;
  short* ob16 = vt16 + 1048576;
  short* x16  = ob16 + 1048576;
  short* ff16 = x16 + 1048576;
  short* WqT = ff16 + 2097152;
  short* WkT = WqT + 262144;
  short* WvT = WkT + 262144;
  short* WoT = WvT + 262144;
  short* W1T = WoT + 262144;
  short* W2T = W1T + 524288;
  short* h1T = W2T + 524288;
  float* wpart = (float*)(h1T + 65536);
  float* po0 = y;
  float* po1 = (float*)ff16;
  float* pl  = lt;

  wconv_all<<<528, 256, 0, stream>>>(Wq, Wk, Wv, Wo, W1, W2, hw1,
                                     WqT, WkT, WvT, WoT, W1T, W2T, h1T);
  embed_kernel<<<TOK_, 128, 0, stream>>>(xyz, ew1, eb1, ew2, eb2, pw1, pb1, pw2, pb2, x);

  dim3 gQKV(12, TOK_ / 64);
  dim3 gDs(D_ / 64, TOK_ / 64, 2);
  dim3 gF(FF_ / 64, TOK_ / 64);
  dim3 gD(D_ / 64, TOK_ / 64);
  for (int l = 0; l < L_; ++l) {
    if (l == 0)
      ln_fused<<<TOK_ / 4, 256, 0, stream>>>(x, nullptr, nullptr, nullptr,
                                             ln1s + l * D_, ln1b + l * D_, x, y16);
    else
      ln_fused<<<TOK_ / 4, 256, 0, stream>>>(x, wpart, wpart + (size_t)TOK_ * D_,
                                             b2 + (l - 1) * D_,
                                             ln1s + l * D_, ln1b + l * D_, x, y16);
    qkv16<<<gQKV, 256, 0, stream>>>(y16, WqT + l * 65536, WkT + l * 65536, WvT + l * 65536,
                                    bq + l * D_, bk + l * D_, bv + l * D_, q16, k16, vt16);
    attn_mfma_kernel<<<1024, 256, 0, stream>>>(q16, k16, vt16, po0, po1, pl);
    wo_split<<<gDs, 256, 0, stream>>>(po0, po1, pl, WoT + l * 65536, wpart);
    ln_fused<<<TOK_ / 4, 256, 0, stream>>>(x, wpart, wpart + (size_t)TOK_ * D_,
                                           bo + l * D_,
                                           ln2s + l * D_, ln2b + l * D_, x, y16);
    gemm16<2, 0><<<gF, 256, 0, stream>>>(y16, W1T + l * 131072, b1 + l * FF_, nullptr, nullptr, ff16, D_, FF_);
    if (l < L_ - 1) {
      gemm16_part<<<gDs, 256, 0, stream>>>(ff16, W2T + l * 131072, wpart, FF_, 256, D_);
    } else {
      gemm16<0, 1><<<gD, 256, 0, stream>>>(ff16, W2T + l * 131072, b2 + l * D_, x, x, x16, FF_, D_);
    }
  }
  gemm16_part<<<gDs, 256, 0, stream>>>(x16, h1T, wpart, D_, 128, HHID_);
  head2_kernel<<<TOK_ / 4, 256, 0, stream>>>(wpart, wpart + (size_t)TOK_ * HHID_,
                                             hb1, hw2, hb2, lt);
  knn_kernel<<<1024, 512, 0, stream>>>(xyz, lt, out);
}